// Round 2
// baseline (271.672 us; speedup 1.0000x reference)
//
#include <hip/hip_runtime.h>
#include <hip/hip_bf16.h>
#include <math.h>

#define Nn   768
#define Ff   64
#define Vv   16
#define NBb  8
#define HRr  64
#define Pp   176
#define TBL  2048
#define ROWF 192   // padded table row (floats): [r1:64][r3:64][16 x (r2,r4,r5,0)]
#define ROW4 48    // row in float4s
#define RMAXF 10.0f
#define AVGF  767.0f

// workspace offsets (in floats)
#define WS_COM 0
#define WS_FLAG 8          // 1.0f => inputs are float32, 0.0f => bf16
#define WS_XP  16          // 768*4 padded positions
#define WS_HS  4096        // h_s   [768][64]
#define WS_HV  53248       // h_v   [768][16][4]
#define WS_HST 102400      // hs_t  [768][64]
#define WS_HVT 151552      // hv_t  [768][16][4]
#define WS_OS  200704      // out_s [768][32]
#define WS_OV  225280      // out_v [768][16][3]
#define WS_TBL 262144      // table [2050][192]

__device__ __forceinline__ float b2f(__hip_bfloat16 v) { return __bfloat162float(v); }

// dtype-adaptive input load
__device__ __forceinline__ float ldin(const void* p, int i, int f32) {
  return f32 ? ((const float*)p)[i]
             : __bfloat162float(((const __hip_bfloat16*)p)[i]);
}

// ------------------------------------------------------------- detect -------
// If the buffer really holds float32, its even bf16-indexed halves are random
// 16-bit mantissa patterns -> ~80% have wild exponents. Genuine bf16 N(0,1)
// data has ~0%. One wave, ballot-reduce.
__global__ void k_detect(const void* __restrict__ x, float* __restrict__ ws) {
  int lane = threadIdx.x;  // 64
  int bad = 0;
  for (int k = 0; k < 2; ++k) {
    float v = b2f(((const __hip_bfloat16*)x)[2 * (lane + 64 * k)]);
    float av = fabsf(v);
    if (!(av <= 1000.0f) || (v != 0.0f && av < 1e-10f)) bad++;
  }
  unsigned long long m1 = __ballot(bad >= 1);
  unsigned long long m2 = __ballot(bad >= 2);
  if (lane == 0) {
    int tot = __popcll(m1) + __popcll(m2);
    ws[WS_FLAG] = (tot > 32) ? 1.0f : 0.0f;
  }
}

// ---------------------------------------------------------------- init ------
__global__ void k_init(const void* __restrict__ x,
                       const void* __restrict__ embed,
                       float* __restrict__ ws) {
  int id = blockIdx.x * blockDim.x + threadIdx.x;
  int stride = gridDim.x * blockDim.x;
  const int f32 = (int)ws[WS_FLAG];
  for (int i = id; i < Nn * Ff; i += stride) ws[WS_HS + i] = ldin(embed, i & (Ff - 1), f32);
  for (int i = id; i < Nn * 64; i += stride) ws[WS_HV + i] = 0.0f;
  for (int i = id; i < Nn * 32; i += stride) ws[WS_OS + i] = 0.0f;
  for (int i = id; i < Nn * 48; i += stride) ws[WS_OV + i] = 0.0f;
  for (int i = id; i < Nn; i += stride) {
    ws[WS_XP + i * 4 + 0] = ldin(x, i * 3 + 0, f32);
    ws[WS_XP + i * 4 + 1] = ldin(x, i * 3 + 1, f32);
    ws[WS_XP + i * 4 + 2] = ldin(x, i * 3 + 2, f32);
    ws[WS_XP + i * 4 + 3] = 0.0f;
  }
}

// ---------------------------------------------------------------- com -------
__global__ void k_com(const void* __restrict__ x, float* __restrict__ ws) {
  __shared__ float red[256][3];
  int tid = threadIdx.x;
  const int f32 = (int)ws[WS_FLAG];
  float a0 = 0.f, a1 = 0.f, a2 = 0.f;
  for (int n = tid; n < Nn; n += 256) {
    a0 += ldin(x, n * 3 + 0, f32);
    a1 += ldin(x, n * 3 + 1, f32);
    a2 += ldin(x, n * 3 + 2, f32);
  }
  red[tid][0] = a0; red[tid][1] = a1; red[tid][2] = a2;
  __syncthreads();
  if (tid < 3) {
    float a = 0.f;
    for (int k = 0; k < 256; ++k) a += red[k][tid];
    ws[WS_COM + tid] = a * (1.0f / Nn);
  }
}

// ------------------------------------------------------------- node ---------
// hs_t = h_s @ w_node_s[t];  hv_t[n][w][c] = sum_v h_v[n][v][c] * w_node_v[t][v][w]
__global__ void k_node(const void* __restrict__ wns,
                       const void* __restrict__ wnv,
                       float* __restrict__ ws, int t) {
  int i = blockIdx.x, tid = threadIdx.x;
  const int f32 = (int)ws[WS_FLAG];
  if (tid < Ff) {
    float a = 0.f;
    for (int k = 0; k < Ff; ++k)
      a += ws[WS_HS + i * Ff + k] * ldin(wns, t * Ff * Ff + k * Ff + tid, f32);
    ws[WS_HST + i * Ff + tid] = a;
  } else {
    int slot = tid - 64;
    int v = slot >> 2, c = slot & 3;
    float a = 0.f;
    if (c < 3) {
      for (int u = 0; u < Vv; ++u)
        a += ws[WS_HV + i * 64 + u * 4 + c] * ldin(wnv, t * Vv * Vv + u * Vv + v, f32);
    }
    ws[WS_HVT + i * 64 + slot] = a;
  }
}

// ------------------------------------------------------------- table --------
// row r = row * RMAX/TBL; R(r) = silu(rb@W1+b1)@W2 * env(r), reordered cols.
__global__ void k_table(const void* __restrict__ w1,
                        const void* __restrict__ b1,
                        const void* __restrict__ w2,
                        float* __restrict__ ws, int t) {
  int row = blockIdx.x, h = threadIdx.x;
  const int f32 = (int)ws[WS_FLAG];
  float r = row * (RMAXF / TBL);
  const float c0 = 0.447213595f;          // sqrt(2/RMAX)
  const float pif = 3.14159265358979f;
  float rb[NBb];
  if (row == 0) {
    for (int n = 0; n < NBb; ++n) rb[n] = c0 * (n + 1) * (pif / RMAXF);
  } else {
    float inv = 1.0f / r;
    for (int n = 0; n < NBb; ++n) rb[n] = c0 * sinf((n + 1) * pif * r / RMAXF) * inv;
  }
  __shared__ float hid[HRr];
  float acc = ldin(b1, t * HRr + h, f32);
  for (int n = 0; n < NBb; ++n) acc += rb[n] * ldin(w1, t * NBb * HRr + n * HRr + h, f32);
  hid[h] = acc / (1.0f + expf(-acc));      // silu
  __syncthreads();
  float u = 2.0f * (1.0f - r / RMAXF);
  float env = (u > 0.0f) ? 1.2f * expf(-1.0f / u) : 0.0f;
  for (int col = h; col < ROWF; col += 64) {
    int p = 0; bool z = false;
    if (col < 64) p = col;
    else if (col < 128) p = 80 + (col - 64);
    else {
      int vv = (col - 128) >> 2, k = (col - 128) & 3;
      if (k == 0) p = 64 + vv;
      else if (k == 1) p = 144 + vv;
      else if (k == 2) p = 160 + vv;
      else z = true;
    }
    float o = 0.0f;
    if (!z) {
      for (int k2 = 0; k2 < HRr; ++k2)
        o += hid[k2] * ldin(w2, t * HRr * Pp + k2 * Pp + p, f32);
      o *= env;
    }
    ws[WS_TBL + row * ROWF + col] = o;
  }
}

// ------------------------------------------------------------- edge ---------
// One block per receiver i. 4 waves x (48 quads x 4 senders). No LDS/barriers
// in the main loop; all reads are coalesced dwordx4 from L2-resident arrays.
__global__ __launch_bounds__(256) void k_edge(
    const void* __restrict__ wmixs,
    const void* __restrict__ wmixv,
    const void* __restrict__ wgate,
    const void* __restrict__ wros,
    const void* __restrict__ wrov,
    float* __restrict__ ws, int t) {
  const int i = blockIdx.x, tid = threadIdx.x;
  const int w = tid >> 6, lane = tid & 63, sq = lane >> 4, idx = lane & 15;
  const int f32 = (int)ws[WS_FLAG];
  const float4* T4  = (const float4*)(ws + WS_TBL);
  const float4* HS4 = (const float4*)(ws + WS_HST);
  const float4* HV4 = (const float4*)(ws + WS_HVT);
  const float4* XP  = (const float4*)(ws + WS_XP);
  const float4 xi = XP[i];

  float s1[4] = {0.f, 0.f, 0.f, 0.f};
  float v1[4][3] = {};
  float s2 = 0.f, v2[3] = {0.f, 0.f, 0.f}, v3[3] = {0.f, 0.f, 0.f};

  const int base0 = w * 192;
  for (int q = 0; q < 48; ++q) {
    int j = base0 + q * 4 + sq;
    float4 xj = XP[j];
    float dx = xi.x - xj.x, dy = xi.y - xj.y, dz = xi.z - xj.z;
    float r2 = dx * dx + dy * dy + dz * dz;
    float rinv = (j == i || r2 <= 0.0f) ? 0.0f : rsqrtf(r2);
    float r = r2 * rinv;
    float hx = dx * rinv, hy = dy * rinv, hz = dz * rinv;
    float u = r * (TBL / RMAXF);
    int i0; float frac;
    if (j != i && u >= 0.0f && u < (float)TBL) {   // NaN-safe: NaN falls through
      i0 = (int)u; frac = u - (float)i0;
    } else {
      i0 = TBL; frac = 0.0f;                        // zero rows
    }
    const float4* ra  = T4 + i0 * ROW4;
    const float4* rbp = ra + ROW4;
    // ---- F-indexed work: features 4*idx..4*idx+3 of sender j
    {
      float4 es  = HS4[j * 16 + idx];
      float4 a1  = ra[idx],      b1v = rbp[idx];
      float4 a3  = ra[16 + idx], b3v = rbp[16 + idx];
      float r1x = a1.x + frac * (b1v.x - a1.x);
      float r1y = a1.y + frac * (b1v.y - a1.y);
      float r1z = a1.z + frac * (b1v.z - a1.z);
      float r1w = a1.w + frac * (b1v.w - a1.w);
      float r3x = a3.x + frac * (b3v.x - a3.x);
      float r3y = a3.y + frac * (b3v.y - a3.y);
      float r3z = a3.z + frac * (b3v.z - a3.z);
      float r3w = a3.w + frac * (b3v.w - a3.w);
      s1[0] += es.x * r1x; s1[1] += es.y * r1y; s1[2] += es.z * r1z; s1[3] += es.w * r1w;
      float ax = es.x * r3x, ay = es.y * r3y, az = es.z * r3z, aw = es.w * r3w;
      v1[0][0] += ax * hx; v1[0][1] += ax * hy; v1[0][2] += ax * hz;
      v1[1][0] += ay * hx; v1[1][1] += ay * hy; v1[1][2] += ay * hz;
      v1[2][0] += az * hx; v1[2][1] += az * hy; v1[2][2] += az * hz;
      v1[3][0] += aw * hx; v1[3][1] += aw * hy; v1[3][2] += aw * hz;
    }
    // ---- V-indexed work: vector channel v = idx of sender j
    {
      float4 ev = HV4[j * 16 + idx];
      float4 av = ra[32 + idx], bv = rbp[32 + idx];
      float rr2 = av.x + frac * (bv.x - av.x);
      float rr4 = av.y + frac * (bv.y - av.y);
      float rr5 = av.z + frac * (bv.z - av.z);
      float dt = ev.x * hx + ev.y * hy + ev.z * hz;
      s2 += dt * rr2;
      v2[0] += ev.x * rr4; v2[1] += ev.y * rr4; v2[2] += ev.z * rr4;
      float cx = ev.y * hz - ev.z * hy;
      float cy = ev.z * hx - ev.x * hz;
      float cz = ev.x * hy - ev.y * hx;
      v3[0] += cx * rr5; v3[1] += cy * rr5; v3[2] += cz * rr5;
    }
  }

  // ---- cross-lane/wave reduction via LDS (once per block)
  __shared__ float acc[256][25];
#pragma unroll
  for (int jj = 0; jj < 4; ++jj) acc[tid][jj] = s1[jj];
#pragma unroll
  for (int jj = 0; jj < 4; ++jj)
#pragma unroll
    for (int c = 0; c < 3; ++c) acc[tid][4 + jj * 3 + c] = v1[jj][c];
  acc[tid][16] = s2;
#pragma unroll
  for (int c = 0; c < 3; ++c) { acc[tid][17 + c] = v2[c]; acc[tid][20 + c] = v3[c]; }
  __syncthreads();

  __shared__ float aggs[80];
  __shared__ float aggv[96][3];
  if (tid < 80) {
    float a = 0.f;
    if (tid < 64) {
      int fq = tid >> 2, jj = tid & 3;
      for (int w2 = 0; w2 < 4; ++w2)
        for (int s = 0; s < 4; ++s) a += acc[w2 * 64 + s * 16 + fq][jj];
    } else {
      int v = tid - 64;
      for (int w2 = 0; w2 < 4; ++w2)
        for (int s = 0; s < 4; ++s) a += acc[w2 * 64 + s * 16 + v][16];
    }
    aggs[tid] = a * (1.0f / AVGF);
  } else if (tid < 176) {
    int p = tid - 80;
    int lidx, slot;
    if (p < 64)      { lidx = p >> 2; slot = 4 + (p & 3) * 3; }
    else if (p < 80) { lidx = p - 64; slot = 17; }
    else             { lidx = p - 80; slot = 20; }
    float a0 = 0.f, a1 = 0.f, a2 = 0.f;
    for (int w2 = 0; w2 < 4; ++w2)
      for (int s = 0; s < 4; ++s) {
        int l = w2 * 64 + s * 16 + lidx;
        a0 += acc[l][slot]; a1 += acc[l][slot + 1]; a2 += acc[l][slot + 2];
      }
    aggv[p][0] = a0 * (1.0f / AVGF);
    aggv[p][1] = a1 * (1.0f / AVGF);
    aggv[p][2] = a2 * (1.0f / AVGF);
  }
  __syncthreads();

  // ---- node update epilogue
  __shared__ float ms[64];
  __shared__ float mvv[16][3];
  __shared__ float gate[16];
  __shared__ float hsn[64];
  __shared__ float hvn[16][3];
  if (tid < 64) {
    float a = 0.f;
    for (int p = 0; p < 80; ++p) a += aggs[p] * ldin(wmixs, t * 80 * 64 + p * 64 + tid, f32);
    ms[tid] = a;
  } else if (tid < 112) {
    int c = (tid - 64) >> 4, v = (tid - 64) & 15;
    float a = 0.f;
    for (int p = 0; p < 96; ++p) a += aggv[p][c] * ldin(wmixv, t * 96 * 16 + p * 16 + v, f32);
    mvv[v][c] = a;
  }
  __syncthreads();
  if (tid < 64) {
    float m = ms[tid];
    float hn = m / (1.0f + expf(-m));
    hsn[tid] = hn;
    ws[WS_HS + i * 64 + tid] = hn;
  } else if (tid < 80) {
    int v = tid - 64;
    float a = 0.f;
    for (int f = 0; f < 64; ++f) a += ms[f] * ldin(wgate, t * 64 * 16 + f * 16 + v, f32);
    gate[v] = 1.0f / (1.0f + expf(-a));
  }
  __syncthreads();
  if (tid < 64) {
    int v = tid >> 2, c = tid & 3;
    float val = (c < 3) ? gate[v] * mvv[v][c] : 0.0f;
    if (c < 3) hvn[v][c] = val;
    ws[WS_HV + i * 64 + tid] = val;
  } else if (tid < 96) {
    int k = tid - 64;
    float a = 0.f;
    for (int f = 0; f < 64; ++f) a += hsn[f] * ldin(wros, t * 64 * 32 + f * 32 + k, f32);
    ws[WS_OS + i * 32 + k] += a;
  }
  __syncthreads();
  if (tid < 48) {
    int c = tid >> 4, k = tid & 15;
    float a = 0.f;
    for (int v = 0; v < 16; ++v) a += hvn[v][c] * ldin(wrov, t * 16 * 16 + v * 16 + k, f32);
    ws[WS_OV + i * 48 + k * 3 + c] += a;
  }
}

// ------------------------------------------------------------- output -------
__global__ void k_out(const float* __restrict__ ws, void* __restrict__ out) {
  int id = blockIdx.x * 256 + threadIdx.x;
  const int f32 = (int)ws[WS_FLAG];
  float val;
  if (id < Nn * 32) {
    val = ws[WS_OS + id];
  } else if (id < Nn * 32 + Nn * 48) {
    int rr = id - Nn * 32;
    int c = rr % 3;
    val = ws[WS_OV + rr] + ws[WS_COM + c];
  } else {
    return;
  }
  if (f32) ((float*)out)[id] = val;
  else     ((__hip_bfloat16*)out)[id] = __float2bfloat16(val);
}

// ------------------------------------------------------------- launch -------
extern "C" void kernel_launch(void* const* d_in, const int* in_sizes, int n_in,
                              void* d_out, int out_size, void* d_ws, size_t ws_size,
                              hipStream_t stream) {
  const void* x     = d_in[0];
  const void* embed = d_in[1];
  const void* wns   = d_in[2];
  const void* wnv   = d_in[3];
  const void* w1    = d_in[4];
  const void* b1    = d_in[5];
  const void* w2    = d_in[6];
  const void* wmixs = d_in[7];
  const void* wmixv = d_in[8];
  const void* wgate = d_in[9];
  const void* wros  = d_in[10];
  const void* wrov  = d_in[11];
  float* ws = (float*)d_ws;

  hipLaunchKernelGGL(k_detect, dim3(1), dim3(64), 0, stream, x, ws);
  hipLaunchKernelGGL(k_init, dim3(192), dim3(256), 0, stream, x, embed, ws);
  hipLaunchKernelGGL(k_com,  dim3(1),   dim3(256), 0, stream, x, ws);
  for (int t = 0; t < 2; ++t) {
    hipLaunchKernelGGL(k_node,  dim3(Nn),      dim3(128), 0, stream, wns, wnv, ws, t);
    hipLaunchKernelGGL(k_table, dim3(TBL + 2), dim3(64),  0, stream, w1, b1, w2, ws, t);
    hipLaunchKernelGGL(k_edge,  dim3(Nn),      dim3(256), 0, stream,
                       wmixs, wmixv, wgate, wros, wrov, ws, t);
  }
  hipLaunchKernelGGL(k_out, dim3(240), dim3(256), 0, stream, ws, d_out);
}

// Round 4
// 174.512 us; speedup vs baseline: 1.5568x; 1.5568x over previous
//
#include <hip/hip_runtime.h>
#include <hip/hip_bf16.h>
#include <math.h>

#define Nn 768
#define Ff 64
#define Vv 16
#define NBb 8
#define HRr 64
#define Pp 176
#define TBL 2048
#define ROWC 192              // table cols per row (padded/permuted)
#define RMAXF 10.0f
#define AVGF 767.0f
#define SCALE 204.8f          // TBL / RMAX

// workspace float offsets
#define WS_COM   0
#define WS_ES0   16
#define WS_XP    128          // 768 x float4
#define WS_HST   4096         // [768][64]
#define WS_HVT   53248        // [768][16][4]
#define WS_OS    102400       // [768][32]
#define WS_OV    126976       // [768][48]
#define WS_AGG   163840       // [768][368] f32, atomically accumulated
#define WS_TBL   458752       // uint region [2049][192]: packed bf16 pairs (a=row, b=row+1)
#define AGGSTRIDE 368

__device__ __forceinline__ unsigned short f2bf(float f) {
  unsigned b = __float_as_uint(f);
  return (unsigned short)((b + 0x7fffu + ((b >> 16) & 1u)) >> 16);
}
__device__ __forceinline__ float lp(unsigned u, float f) {
  float a = __uint_as_float(u << 16);
  float b = __uint_as_float(u & 0xffff0000u);
  return fmaf(f, b - a, a);
}

// ---------------------------------------------------------------- pre -------
__global__ void k_pre(const float* __restrict__ x, const float* __restrict__ embed,
                      const float* __restrict__ wns, float* __restrict__ ws) {
  int b = blockIdx.x, tid = threadIdx.x;
  if (b == 0) {                       // center of mass
    __shared__ float red[256][3];
    float a0 = 0, a1 = 0, a2 = 0;
    for (int n = tid; n < Nn; n += 256) {
      a0 += x[n * 3 + 0]; a1 += x[n * 3 + 1]; a2 += x[n * 3 + 2];
    }
    red[tid][0] = a0; red[tid][1] = a1; red[tid][2] = a2;
    __syncthreads();
    if (tid < 3) {
      float a = 0;
      for (int k = 0; k < 256; ++k) a += red[k][tid];
      ws[WS_COM + tid] = a * (1.0f / Nn);
    }
  } else if (b == 1) {                // padded positions
    for (int n = tid; n < Nn; n += 256) {
      ws[WS_XP + n * 4 + 0] = x[n * 3 + 0];
      ws[WS_XP + n * 4 + 1] = x[n * 3 + 1];
      ws[WS_XP + n * 4 + 2] = x[n * 3 + 2];
      ws[WS_XP + n * 4 + 3] = 0.0f;
    }
  } else {                            // es0 = embed @ wns[0] (layer-0 sender feats)
    if (tid < 64) {
      float a = 0;
      for (int k = 0; k < 64; ++k) a = fmaf(embed[k], wns[k * 64 + tid], a);
      ws[WS_ES0 + tid] = a;
    }
  }
}

// ------------------------------------------------------------- table --------
// 256 blocks x 256 thr; block handles pair-rows r0..r0+7 (needs hid rows r0..r0+8).
// Packed u32: low16 = bf16(R(row)[col]), high16 = bf16(R(row+1)[col]).
__global__ __launch_bounds__(256) void k_table(const float* __restrict__ w1,
                                               const float* __restrict__ b1,
                                               const float* __restrict__ w2,
                                               float* __restrict__ ws, int t) {
  __shared__ float w2s[64][Pp];
  __shared__ float w1s[NBb][64];
  __shared__ float b1s[64];
  __shared__ float hid[9][65];
  const int tid = threadIdx.x;
  const int r0 = blockIdx.x * 8;
  const float* W2 = w2 + t * HRr * Pp;
  for (int k = tid; k < 64 * Pp; k += 256) w2s[k / Pp][k % Pp] = W2[k];
  for (int k = tid; k < NBb * 64; k += 256) w1s[k >> 6][k & 63] = w1[t * NBb * 64 + k];
  if (tid < 64) b1s[tid] = b1[t * 64 + tid];
  __syncthreads();
  {
    int rl4 = tid >> 6, h = tid & 63;
    const float c0 = 0.447213595f;               // sqrt(2/RMAX)
    const float pif = 3.14159265358979f;
    for (int pass = 0; pass < 3; ++pass) {
      int row_l = pass * 4 + rl4;
      if (row_l < 9) {
        int row = r0 + row_l;
        float r = row * (RMAXF / TBL);
        float acc = b1s[h];
        if (row == 0) {
          for (int n = 0; n < NBb; ++n) acc = fmaf(c0 * (n + 1) * (pif / RMAXF), w1s[n][h], acc);
        } else {
          float inv = 1.0f / r;
          for (int n = 0; n < NBb; ++n)
            acc = fmaf(c0 * sinf((n + 1) * pif * r / RMAXF) * inv, w1s[n][h], acc);
        }
        hid[row_l][h] = acc / (1.0f + expf(-acc));
      }
    }
  }
  __syncthreads();
  unsigned* T = (unsigned*)(ws + WS_TBL);
  const int rl = tid & 7, colg = tid >> 3;
  const int rowa = r0 + rl;
  float ra = rowa * (RMAXF / TBL), rb = (rowa + 1) * (RMAXF / TBL);
  float ua = 2.0f * (1.0f - ra / RMAXF), ub = 2.0f * (1.0f - rb / RMAXF);
  float env_a = (ua > 0.0f) ? 1.2f * expf(-1.0f / ua) : 0.0f;
  float env_b = (ub > 0.0f) ? 1.2f * expf(-1.0f / ub) : 0.0f;
  float accA[6], accB[6];
  int pcol[6]; bool zc[6];
#pragma unroll
  for (int c = 0; c < 6; ++c) {
    int col = colg * 6 + c;
    int p = 0; bool z = false;
    if (col < 64) p = col;
    else if (col < 128) p = 80 + (col - 64);
    else {
      int vv = (col - 128) >> 2, k = (col - 128) & 3;
      if (k == 0) p = 64 + vv; else if (k == 1) p = 144 + vv;
      else if (k == 2) p = 160 + vv; else z = true;
    }
    pcol[c] = p; zc[c] = z; accA[c] = 0.0f; accB[c] = 0.0f;
  }
  for (int h = 0; h < 64; ++h) {
    float ha = hid[rl][h], hb = hid[rl + 1][h];
#pragma unroll
    for (int c = 0; c < 6; ++c) {
      float w = w2s[h][pcol[c]];
      accA[c] = fmaf(ha, w, accA[c]);
      accB[c] = fmaf(hb, w, accB[c]);
    }
  }
#pragma unroll
  for (int c = 0; c < 6; ++c) {
    int col = colg * 6 + c;
    float va = zc[c] ? 0.0f : accA[c] * env_a;
    float vb = zc[c] ? 0.0f : accB[c] * env_b;
    T[rowa * ROWC + col] = ((unsigned)f2bf(vb) << 16) | (unsigned)f2bf(va);
  }
  if (blockIdx.x == 255) {                       // zero pair-row 2048 (self / r>=RMAX)
    for (int k = tid; k < ROWC; k += 256) T[2048 * ROWC + k] = 0u;
  }
}

// ------------------------------------------------------------- edge t=0 -----
// 3072 blocks (4 per receiver). Only r1/r3 columns needed (es uniform, ev=0).
__global__ __launch_bounds__(256) void k_edge0(float* __restrict__ ws) {
  const int blk = blockIdx.x, i = blk >> 2, part = blk & 3;
  const int tid = threadIdx.x;
  const int w = tid >> 6, lane = tid & 63, sq = (lane >> 4) & 3, idx = lane & 15;
  __shared__ float4 GEO[192];
  __shared__ float wb[4][16][16];
  const float4* XP4 = (const float4*)(ws + WS_XP);
  const uint4* T4 = (const uint4*)(ws + WS_TBL);
  const float4 xi = XP4[i];
  if (tid < 192) {
    int j = part * 192 + tid;
    float4 xj = XP4[j];
    float dx = xi.x - xj.x, dy = xi.y - xj.y, dz = xi.z - xj.z;
    float r2 = dx * dx + dy * dy + dz * dz;
    float u, hx, hy, hz;
    if (j == i || r2 <= 0.0f) { u = 2048.0f; hx = hy = hz = 0.0f; }
    else {
      float rinv = rsqrtf(r2);
      hx = dx * rinv; hy = dy * rinv; hz = dz * rinv;
      u = fminf(r2 * rinv * SCALE, 2048.0f);
    }
    GEO[tid] = make_float4(hx, hy, hz, u);
  }
  __syncthreads();
  float s1[4] = {0, 0, 0, 0};
  float v1[4][3] = {};
  for (int q = 0; q < 12; ++q) {
    int jl = w * 48 + q * 4 + sq;
    float4 g = GEO[jl];
    int i0 = (int)g.w;
    float fr = g.w - (float)i0;
    const uint4* rp = T4 + i0 * 48;
    uint4 t1 = rp[idx];
    uint4 t3 = rp[16 + idx];
    s1[0] += lp(t1.x, fr); s1[1] += lp(t1.y, fr);
    s1[2] += lp(t1.z, fr); s1[3] += lp(t1.w, fr);
    float ax = lp(t3.x, fr), ay = lp(t3.y, fr), az = lp(t3.z, fr), aw = lp(t3.w, fr);
    v1[0][0] += ax * g.x; v1[0][1] += ax * g.y; v1[0][2] += ax * g.z;
    v1[1][0] += ay * g.x; v1[1][1] += ay * g.y; v1[1][2] += ay * g.z;
    v1[2][0] += az * g.x; v1[2][1] += az * g.y; v1[2][2] += az * g.z;
    v1[3][0] += aw * g.x; v1[3][1] += aw * g.y; v1[3][2] += aw * g.z;
  }
  float vals[16] = {s1[0], s1[1], s1[2], s1[3],
                    v1[0][0], v1[0][1], v1[0][2], v1[1][0], v1[1][1], v1[1][2],
                    v1[2][0], v1[2][1], v1[2][2], v1[3][0], v1[3][1], v1[3][2]};
#pragma unroll
  for (int k = 0; k < 16; ++k) {
    float v = vals[k];
    v += __shfl_xor(v, 16);
    v += __shfl_xor(v, 32);
    if (lane < 16) wb[w][lane][k] = v;
  }
  __syncthreads();
  {
    int l, s;
    if (tid < 64) { l = tid >> 2; s = tid & 3; }
    else { int p = tid - 64, f = p / 3, c = p - 3 * f; l = f >> 2; s = 4 + 3 * (f & 3) + c; }
    float a = wb[0][l][s] + wb[1][l][s] + wb[2][l][s] + wb[3][l][s];
    atomicAdd(&ws[WS_AGG + i * AGGSTRIDE + tid], a);
  }
}

// ------------------------------------------------------------- edge t=1 -----
__global__ __launch_bounds__(256) void k_edge1(float* __restrict__ ws) {
  const int blk = blockIdx.x, i = blk >> 2, part = blk & 3;
  const int tid = threadIdx.x;
  const int w = tid >> 6, lane = tid & 63, sq = (lane >> 4) & 3, idx = lane & 15;
  __shared__ float4 GEO[192];
  __shared__ float wb[4][16][24];
  const float4* XP4 = (const float4*)(ws + WS_XP);
  const uint4* T4 = (const uint4*)(ws + WS_TBL);
  const float4* HS4 = (const float4*)(ws + WS_HST);
  const float4* HV4 = (const float4*)(ws + WS_HVT);
  const float4 xi = XP4[i];
  if (tid < 192) {
    int j = part * 192 + tid;
    float4 xj = XP4[j];
    float dx = xi.x - xj.x, dy = xi.y - xj.y, dz = xi.z - xj.z;
    float r2 = dx * dx + dy * dy + dz * dz;
    float u, hx, hy, hz;
    if (j == i || r2 <= 0.0f) { u = 2048.0f; hx = hy = hz = 0.0f; }
    else {
      float rinv = rsqrtf(r2);
      hx = dx * rinv; hy = dy * rinv; hz = dz * rinv;
      u = fminf(r2 * rinv * SCALE, 2048.0f);
    }
    GEO[tid] = make_float4(hx, hy, hz, u);
  }
  __syncthreads();
  float s1[4] = {0, 0, 0, 0};
  float v1[4][3] = {};
  float s2 = 0, v2x = 0, v2y = 0, v2z = 0, v3x = 0, v3y = 0, v3z = 0;
  const int jbase = part * 192;
  for (int q = 0; q < 12; ++q) {
    int jl = w * 48 + q * 4 + sq;
    float4 g = GEO[jl];
    int i0 = (int)g.w;
    float fr = g.w - (float)i0;
    const uint4* rp = T4 + i0 * 48;
    uint4 t1 = rp[idx];
    uint4 t3 = rp[16 + idx];
    uint4 tv = rp[32 + idx];
    int jg = jbase + jl;
    float4 es = HS4[jg * 16 + idx];
    float4 ev = HV4[jg * 16 + idx];
    s1[0] += es.x * lp(t1.x, fr); s1[1] += es.y * lp(t1.y, fr);
    s1[2] += es.z * lp(t1.z, fr); s1[3] += es.w * lp(t1.w, fr);
    float ax = es.x * lp(t3.x, fr), ay = es.y * lp(t3.y, fr);
    float az = es.z * lp(t3.z, fr), aw = es.w * lp(t3.w, fr);
    v1[0][0] += ax * g.x; v1[0][1] += ax * g.y; v1[0][2] += ax * g.z;
    v1[1][0] += ay * g.x; v1[1][1] += ay * g.y; v1[1][2] += ay * g.z;
    v1[2][0] += az * g.x; v1[2][1] += az * g.y; v1[2][2] += az * g.z;
    v1[3][0] += aw * g.x; v1[3][1] += aw * g.y; v1[3][2] += aw * g.z;
    float rr2 = lp(tv.x, fr), rr4 = lp(tv.y, fr), rr5 = lp(tv.z, fr);
    float dt = ev.x * g.x + ev.y * g.y + ev.z * g.z;
    s2 += dt * rr2;
    v2x += ev.x * rr4; v2y += ev.y * rr4; v2z += ev.z * rr4;
    v3x += (ev.y * g.z - ev.z * g.y) * rr5;
    v3y += (ev.z * g.x - ev.x * g.z) * rr5;
    v3z += (ev.x * g.y - ev.y * g.x) * rr5;
  }
  float vals[23] = {s1[0], s1[1], s1[2], s1[3],
                    v1[0][0], v1[0][1], v1[0][2], v1[1][0], v1[1][1], v1[1][2],
                    v1[2][0], v1[2][1], v1[2][2], v1[3][0], v1[3][1], v1[3][2],
                    s2, v2x, v2y, v2z, v3x, v3y, v3z};
#pragma unroll
  for (int k = 0; k < 23; ++k) {
    float v = vals[k];
    v += __shfl_xor(v, 16);
    v += __shfl_xor(v, 32);
    if (lane < 16) wb[w][lane][k] = v;
  }
  __syncthreads();
  // FIX: 368 slots with 256 threads -> strided loop (was `if (tid < 368)`,
  // which silently dropped slots 256..367)
  for (int s = tid; s < 368; s += 256) {
    int l, sl;
    if (s < 64) { l = s >> 2; sl = s & 3; }
    else if (s < 80) { l = s - 64; sl = 16; }
    else if (s < 272) { int p = s - 80, f = p / 3, c = p - 3 * f; l = f >> 2; sl = 4 + 3 * (f & 3) + c; }
    else if (s < 320) { int p = s - 272, v = p / 3, c = p - 3 * v; l = v; sl = 17 + c; }
    else { int p = s - 320, v = p / 3, c = p - 3 * v; l = v; sl = 20 + c; }
    float a = wb[0][l][sl] + wb[1][l][sl] + wb[2][l][sl] + wb[3][l][sl];
    atomicAdd(&ws[WS_AGG + i * AGGSTRIDE + s], a);
  }
}

// ------------------------------------------------------------- post ---------
// Node update + readout; t=0 additionally fuses layer-1 node transforms.
__global__ __launch_bounds__(256) void k_post(const float* __restrict__ wns,
                                              const float* __restrict__ wnv,
                                              const float* __restrict__ wmixs,
                                              const float* __restrict__ wmixv,
                                              const float* __restrict__ wgate,
                                              const float* __restrict__ wros,
                                              const float* __restrict__ wrov,
                                              float* __restrict__ ws,
                                              float* __restrict__ out, int t) {
  const int i = blockIdx.x, tid = threadIdx.x;
  __shared__ float agg[368];
  __shared__ float ms[64], mvv[16][3], gate[16], hsn[64], hvn[16][4];
  const float inv = 1.0f / AVGF;
  const float* A = ws + WS_AGG + i * AGGSTRIDE;
  // FIX: 368 slots with 256 threads -> strided loop (was `if (tid < 368)`,
  // leaving agg[256..367] (t=1) / agg[272..367] (t=0) as LDS garbage)
  if (t == 0) {
    for (int s = tid; s < 368; s += 256) {
      float val;
      if (s < 64) val = ws[WS_ES0 + s] * A[s] * inv;
      else if (s < 80) val = 0.0f;
      else if (s < 272) { int p = s - 80, f = p / 3; val = ws[WS_ES0 + f] * A[64 + p] * inv; }
      else val = 0.0f;
      agg[s] = val;
    }
  } else {
    for (int s = tid; s < 368; s += 256) agg[s] = A[s] * inv;
  }
  __syncthreads();
  if (tid < 64) {
    const float* Wm = wmixs + t * 80 * 64;
    float a = 0;
    for (int p = 0; p < 80; ++p) a = fmaf(agg[p], Wm[p * 64 + tid], a);
    ms[tid] = a;
  } else if (tid < 112) {
    int c = (tid - 64) >> 4, v = (tid - 64) & 15;
    const float* Wv = wmixv + t * 96 * 16;
    float a = 0;
    for (int p = 0; p < 96; ++p) {
      int ai = (p < 64) ? (80 + p * 3 + c) : (p < 80 ? (272 + (p - 64) * 3 + c)
                                                     : (320 + (p - 80) * 3 + c));
      a = fmaf(agg[ai], Wv[p * 16 + v], a);
    }
    mvv[v][c] = a;
  }
  __syncthreads();
  if (tid < 64) {
    float m = ms[tid];
    hsn[tid] = m / (1.0f + expf(-m));
  } else if (tid < 80) {
    int v = tid - 64;
    const float* Wg = wgate + t * 64 * 16;
    float a = 0;
    for (int f = 0; f < 64; ++f) a = fmaf(ms[f], Wg[f * 16 + v], a);
    gate[v] = 1.0f / (1.0f + expf(-a));
  }
  __syncthreads();
  if (tid < 64) {
    int v = tid >> 2, c = tid & 3;
    hvn[v][c] = (c < 3) ? gate[v] * mvv[v][c] : 0.0f;
  }
  __syncthreads();
  if (t == 0) {
    if (tid < 32) {
      float a = 0;
      for (int f = 0; f < 64; ++f) a = fmaf(hsn[f], wros[f * 32 + tid], a);
      ws[WS_OS + i * 32 + tid] = a;
    } else if (tid < 80) {
      int p = tid - 32, k = p / 3, c = p - 3 * k;
      float a = 0;
      for (int v = 0; v < 16; ++v) a = fmaf(hvn[v][c], wrov[v * 16 + k], a);
      ws[WS_OV + i * 48 + p] = a;
    } else if (tid < 144) {
      int f2 = tid - 80;
      const float* Wn = wns + 64 * 64;            // wns[1]
      float a = 0;
      for (int f = 0; f < 64; ++f) a = fmaf(hsn[f], Wn[f * 64 + f2], a);
      ws[WS_HST + i * 64 + f2] = a;
    } else if (tid < 208) {
      int s = tid - 144, wv = s >> 2, c = s & 3;
      float a = 0;
      if (c < 3) {
        const float* Wn = wnv + 16 * 16;          // wnv[1]
        for (int v = 0; v < 16; ++v) a = fmaf(hvn[v][c], Wn[v * 16 + wv], a);
      }
      ws[WS_HVT + i * 64 + s] = a;
    }
  } else {
    if (tid < 32) {
      const float* Wr = wros + 64 * 32;
      float a = ws[WS_OS + i * 32 + tid];
      for (int f = 0; f < 64; ++f) a = fmaf(hsn[f], Wr[f * 32 + tid], a);
      out[i * 32 + tid] = a;
    } else if (tid < 80) {
      int p = tid - 32, k = p / 3, c = p - 3 * k;
      const float* Wr = wrov + 16 * 16;
      float a = ws[WS_OV + i * 48 + p] + ws[WS_COM + c];
      for (int v = 0; v < 16; ++v) a = fmaf(hvn[v][c], Wr[v * 16 + k], a);
      out[Nn * 32 + i * 48 + p] = a;
    }
  }
}

// ------------------------------------------------------------- launch -------
extern "C" void kernel_launch(void* const* d_in, const int* in_sizes, int n_in,
                              void* d_out, int out_size, void* d_ws, size_t ws_size,
                              hipStream_t stream) {
  const float* x     = (const float*)d_in[0];
  const float* embed = (const float*)d_in[1];
  const float* wns   = (const float*)d_in[2];
  const float* wnv   = (const float*)d_in[3];
  const float* w1    = (const float*)d_in[4];
  const float* b1    = (const float*)d_in[5];
  const float* w2    = (const float*)d_in[6];
  const float* wmixs = (const float*)d_in[7];
  const float* wmixv = (const float*)d_in[8];
  const float* wgate = (const float*)d_in[9];
  const float* wros  = (const float*)d_in[10];
  const float* wrov  = (const float*)d_in[11];
  float* ws = (float*)d_ws;
  float* out = (float*)d_out;

  hipMemsetAsync(ws + WS_AGG, 0, Nn * AGGSTRIDE * sizeof(float), stream);
  hipLaunchKernelGGL(k_pre,   dim3(3),      dim3(256), 0, stream, x, embed, wns, ws);
  hipLaunchKernelGGL(k_table, dim3(256),    dim3(256), 0, stream, w1, b1, w2, ws, 0);
  hipLaunchKernelGGL(k_edge0, dim3(Nn * 4), dim3(256), 0, stream, ws);
  hipLaunchKernelGGL(k_post,  dim3(Nn),     dim3(256), 0, stream,
                     wns, wnv, wmixs, wmixv, wgate, wros, wrov, ws, out, 0);
  hipMemsetAsync(ws + WS_AGG, 0, Nn * AGGSTRIDE * sizeof(float), stream);
  hipLaunchKernelGGL(k_table, dim3(256),    dim3(256), 0, stream, w1, b1, w2, ws, 1);
  hipLaunchKernelGGL(k_edge1, dim3(Nn * 4), dim3(256), 0, stream, ws);
  hipLaunchKernelGGL(k_post,  dim3(Nn),     dim3(256), 0, stream,
                     wns, wnv, wmixs, wmixv, wgate, wros, wrov, ws, out, 1);
}

// Round 5
// 155.343 us; speedup vs baseline: 1.7489x; 1.1234x over previous
//
#include <hip/hip_runtime.h>
#include <hip/hip_bf16.h>
#include <math.h>

#define Nn 768
#define Ff 64
#define Vv 16
#define NBb 8
#define HRr 64
#define Pp 176
#define TBL 2048
#define ROWC 192              // table cols per row (padded/permuted), uints
#define RMAXF 10.0f
#define AVGF 767.0f
#define SCALE 204.8f          // TBL / RMAX

// workspace float offsets
#define WS_COM   0
#define WS_ES0   16
#define WS_XP    128          // 768 x float4
#define WS_HSB   4096         // uint2[768][16]  : h_s^1 packed bf16 (4/uint2)
#define WS_HVB   28672        // uint2[768][16]  : h_v^1 packed bf16 (x,y,z,0)
#define WS_OS    53248        // [768][32] layer-0 scalar readout
#define WS_OV    77824        // [768][48] layer-0 vector readout ([k][c])
#define WS_SLAB0 131072       // float[4][768][256]
#define WS_SLAB1 917504       // float[4][768][384] (368 used)
#define WS_TBL   2097152      // unsigned[2][2049][192]: packed bf16 pairs

__device__ __forceinline__ unsigned short f2bf(float f) {
  unsigned b = __float_as_uint(f);
  return (unsigned short)((b + 0x7fffu + ((b >> 16) & 1u)) >> 16);
}
__device__ __forceinline__ float lp(unsigned u, float f) {   // lerp packed pair
  float a = __uint_as_float(u << 16);
  float b = __uint_as_float(u & 0xffff0000u);
  return fmaf(f, b - a, a);
}
__device__ __forceinline__ float bl(unsigned u) { return __uint_as_float(u << 16); }
__device__ __forceinline__ float bh(unsigned u) { return __uint_as_float(u & 0xffff0000u); }

// ---------------------------------------------------------------- setup -----
// blocks 0..511: radial tables for t=0/1 (t = b>>8, pair-rows (b&255)*8 ..+7)
// block 512: center of mass; 513: padded positions; 514: es0 = embed @ wns[0]
__global__ __launch_bounds__(256) void k_setup(const float* __restrict__ x,
                                               const float* __restrict__ embed,
                                               const float* __restrict__ wns,
                                               const float* __restrict__ w1,
                                               const float* __restrict__ b1,
                                               const float* __restrict__ w2,
                                               float* __restrict__ ws) {
  const int b = blockIdx.x, tid = threadIdx.x;
  if (b >= 512) {
    if (b == 512) {
      __shared__ float red[256][3];
      float a0 = 0, a1 = 0, a2 = 0;
      for (int n = tid; n < Nn; n += 256) {
        a0 += x[n * 3 + 0]; a1 += x[n * 3 + 1]; a2 += x[n * 3 + 2];
      }
      red[tid][0] = a0; red[tid][1] = a1; red[tid][2] = a2;
      __syncthreads();
      if (tid < 3) {
        float a = 0;
        for (int k = 0; k < 256; ++k) a += red[k][tid];
        ws[WS_COM + tid] = a * (1.0f / Nn);
      }
    } else if (b == 513) {
      for (int n = tid; n < Nn; n += 256) {
        ws[WS_XP + n * 4 + 0] = x[n * 3 + 0];
        ws[WS_XP + n * 4 + 1] = x[n * 3 + 1];
        ws[WS_XP + n * 4 + 2] = x[n * 3 + 2];
        ws[WS_XP + n * 4 + 3] = 0.0f;
      }
    } else {
      if (tid < 64) {
        float a = 0;
        for (int k = 0; k < 64; ++k) a = fmaf(embed[k], wns[k * 64 + tid], a);
        ws[WS_ES0 + tid] = a;
      }
    }
    return;
  }
  // ---- table block
  __shared__ float w2s[64][Pp];
  __shared__ float w1s[NBb][64];
  __shared__ float b1s[64];
  __shared__ float hid[9][65];
  const int t = b >> 8;
  const int r0 = (b & 255) * 8;
  const float* W2 = w2 + t * HRr * Pp;
  for (int k = tid; k < 64 * Pp; k += 256) w2s[k / Pp][k % Pp] = W2[k];
  for (int k = tid; k < NBb * 64; k += 256) w1s[k >> 6][k & 63] = w1[t * NBb * 64 + k];
  if (tid < 64) b1s[tid] = b1[t * 64 + tid];
  __syncthreads();
  {
    int rl4 = tid >> 6, h = tid & 63;
    const float c0 = 0.447213595f;               // sqrt(2/RMAX)
    const float pif = 3.14159265358979f;
    for (int pass = 0; pass < 3; ++pass) {
      int row_l = pass * 4 + rl4;
      if (row_l < 9) {
        int row = r0 + row_l;
        float r = row * (RMAXF / TBL);
        float acc = b1s[h];
        if (row == 0) {
          for (int n = 0; n < NBb; ++n) acc = fmaf(c0 * (n + 1) * (pif / RMAXF), w1s[n][h], acc);
        } else {
          float inv = 1.0f / r;
          for (int n = 0; n < NBb; ++n)
            acc = fmaf(c0 * sinf((n + 1) * pif * r / RMAXF) * inv, w1s[n][h], acc);
        }
        hid[row_l][h] = acc / (1.0f + expf(-acc));
      }
    }
  }
  __syncthreads();
  unsigned* T = (unsigned*)(ws + WS_TBL) + t * 2049 * ROWC;
  const int rl = tid & 7, colg = tid >> 3;
  const int rowa = r0 + rl;
  float ra = rowa * (RMAXF / TBL), rb = (rowa + 1) * (RMAXF / TBL);
  float ua = 2.0f * (1.0f - ra / RMAXF), ub = 2.0f * (1.0f - rb / RMAXF);
  float env_a = (ua > 0.0f) ? 1.2f * expf(-1.0f / ua) : 0.0f;
  float env_b = (ub > 0.0f) ? 1.2f * expf(-1.0f / ub) : 0.0f;
  float accA[6], accB[6];
  int pcol[6]; bool zc[6];
#pragma unroll
  for (int c = 0; c < 6; ++c) {
    int col = colg * 6 + c;
    int p = 0; bool z = false;
    if (col < 64) p = col;
    else if (col < 128) p = 80 + (col - 64);
    else {
      int vv = (col - 128) >> 2, k = (col - 128) & 3;
      if (k == 0) p = 64 + vv; else if (k == 1) p = 144 + vv;
      else if (k == 2) p = 160 + vv; else z = true;
    }
    pcol[c] = p; zc[c] = z; accA[c] = 0.0f; accB[c] = 0.0f;
  }
  for (int h = 0; h < 64; ++h) {
    float ha = hid[rl][h], hb = hid[rl + 1][h];
#pragma unroll
    for (int c = 0; c < 6; ++c) {
      float w = w2s[h][pcol[c]];
      accA[c] = fmaf(ha, w, accA[c]);
      accB[c] = fmaf(hb, w, accB[c]);
    }
  }
#pragma unroll
  for (int c = 0; c < 6; ++c) {
    int col = colg * 6 + c;
    float va = zc[c] ? 0.0f : accA[c] * env_a;
    float vb = zc[c] ? 0.0f : accB[c] * env_b;
    T[rowa * ROWC + col] = ((unsigned)f2bf(vb) << 16) | (unsigned)f2bf(va);
  }
  if ((b & 255) == 255) {                        // zero pair-row 2048
    for (int k = tid; k < ROWC; k += 256) T[2048 * ROWC + k] = 0u;
  }
}

// ------------------------------------------------------------- edge t=0 -----
// 3072 blocks (4 parts/receiver). Only r1/r3 columns (es uniform, ev=0).
// Partial sums -> private slab (no atomics).
__global__ __launch_bounds__(256) void k_edge0(float* __restrict__ ws) {
  const int blk = blockIdx.x, i = blk >> 2, part = blk & 3;
  const int tid = threadIdx.x;
  const int w = tid >> 6, lane = tid & 63, sq = (lane >> 4) & 3, idx = lane & 15;
  __shared__ float4 GEO[192];
  __shared__ float wb[4][16][17];    // odd stride: conflict-free
  const float4* XP4 = (const float4*)(ws + WS_XP);
  const uint4* T4 = (const uint4*)(ws + WS_TBL);
  const float4 xi = XP4[i];
  if (tid < 192) {
    int j = part * 192 + tid;
    float4 xj = XP4[j];
    float dx = xi.x - xj.x, dy = xi.y - xj.y, dz = xi.z - xj.z;
    float r2 = dx * dx + dy * dy + dz * dz;
    float u, hx, hy, hz;
    if (j == i || r2 <= 0.0f) { u = 2048.0f; hx = hy = hz = 0.0f; }
    else {
      float rinv = rsqrtf(r2);
      hx = dx * rinv; hy = dy * rinv; hz = dz * rinv;
      u = fminf(r2 * rinv * SCALE, 2048.0f);
    }
    GEO[tid] = make_float4(hx, hy, hz, u);
  }
  __syncthreads();
  float s1[4] = {0, 0, 0, 0};
  float v1[4][3] = {};
  for (int q = 0; q < 12; ++q) {
    int jl = w * 48 + q * 4 + sq;
    float4 g = GEO[jl];
    int i0 = (int)g.w;
    float fr = g.w - (float)i0;
    const uint4* rp = T4 + i0 * 48;
    uint4 t1 = rp[idx];
    uint4 t3 = rp[16 + idx];
    s1[0] += lp(t1.x, fr); s1[1] += lp(t1.y, fr);
    s1[2] += lp(t1.z, fr); s1[3] += lp(t1.w, fr);
    float ax = lp(t3.x, fr), ay = lp(t3.y, fr), az = lp(t3.z, fr), aw = lp(t3.w, fr);
    v1[0][0] += ax * g.x; v1[0][1] += ax * g.y; v1[0][2] += ax * g.z;
    v1[1][0] += ay * g.x; v1[1][1] += ay * g.y; v1[1][2] += ay * g.z;
    v1[2][0] += az * g.x; v1[2][1] += az * g.y; v1[2][2] += az * g.z;
    v1[3][0] += aw * g.x; v1[3][1] += aw * g.y; v1[3][2] += aw * g.z;
  }
  float vals[16] = {s1[0], s1[1], s1[2], s1[3],
                    v1[0][0], v1[0][1], v1[0][2], v1[1][0], v1[1][1], v1[1][2],
                    v1[2][0], v1[2][1], v1[2][2], v1[3][0], v1[3][1], v1[3][2]};
#pragma unroll
  for (int k = 0; k < 16; ++k) {
    float v = vals[k];
    v += __shfl_xor(v, 16);
    v += __shfl_xor(v, 32);
    if (lane < 16) wb[w][lane][k] = v;
  }
  __syncthreads();
  {
    int l, s;
    if (tid < 64) { l = tid >> 2; s = tid & 3; }
    else { int p = tid - 64, f = p / 3, c = p - 3 * f; l = f >> 2; s = 4 + 3 * (f & 3) + c; }
    float a = wb[0][l][s] + wb[1][l][s] + wb[2][l][s] + wb[3][l][s];
    ws[WS_SLAB0 + (part * Nn + i) * 256 + tid] = a;
  }
}

// ------------------------------------------------------------- post t=0 -----
// Sum slabs, apply es0, node update, layer-0 readout, layer-1 node transforms
// packed to bf16 for k_edge1.
__global__ __launch_bounds__(256) void k_post0(const float* __restrict__ wns,
                                               const float* __restrict__ wnv,
                                               const float* __restrict__ wmixs,
                                               const float* __restrict__ wmixv,
                                               const float* __restrict__ wgate,
                                               const float* __restrict__ wros,
                                               const float* __restrict__ wrov,
                                               float* __restrict__ ws) {
  const int i = blockIdx.x, tid = threadIdx.x;
  __shared__ float agg[256];
  __shared__ float ms[64], mvv[16][3], gate[16], hsn[64], hvns[16][4];
  __shared__ float hs1s[64], hv1s[16][4];
  const float inv = 1.0f / AVGF;
  const float* S = ws + WS_SLAB0 + i * 256;
  {
    float a = S[tid] + S[Nn * 256 + tid] + S[2 * Nn * 256 + tid] + S[3 * Nn * 256 + tid];
    float es0f = (tid < 64) ? ws[WS_ES0 + tid] : ws[WS_ES0 + (tid - 64) / 3];
    agg[tid] = a * inv * es0f;
  }
  __syncthreads();
  if (tid < 64) {                    // rows 64..79 of wmixs are x dot-slots = 0 at t=0
    const float* Wm = wmixs;
    float a = 0;
    for (int p = 0; p < 64; ++p) a = fmaf(agg[p], Wm[p * 64 + tid], a);
    ms[tid] = a;
  } else if (tid < 112) {            // rows 64..95 of wmixv are v2/v3 = 0 at t=0
    int c = (tid - 64) >> 4, v = (tid - 64) & 15;
    const float* Wv = wmixv;
    float a = 0;
    for (int p = 0; p < 64; ++p) a = fmaf(agg[64 + p * 3 + c], Wv[p * 16 + v], a);
    mvv[v][c] = a;
  }
  __syncthreads();
  if (tid < 64) {
    float m = ms[tid];
    hsn[tid] = m / (1.0f + expf(-m));
  } else if (tid < 80) {
    int v = tid - 64;
    float a = 0;
    for (int f = 0; f < 64; ++f) a = fmaf(ms[f], wgate[f * 16 + v], a);
    gate[v] = 1.0f / (1.0f + expf(-a));
  }
  __syncthreads();
  if (tid < 64) {
    int v = tid >> 2, c = tid & 3;
    hvns[v][c] = (c < 3) ? gate[v] * mvv[v][c] : 0.0f;
  }
  __syncthreads();
  if (tid < 32) {
    float a = 0;
    for (int f = 0; f < 64; ++f) a = fmaf(hsn[f], wros[f * 32 + tid], a);
    ws[WS_OS + i * 32 + tid] = a;
  } else if (tid < 80) {
    int p = tid - 32, k = p / 3, c = p - 3 * k;
    float a = 0;
    for (int v = 0; v < 16; ++v) a = fmaf(hvns[v][c], wrov[v * 16 + k], a);
    ws[WS_OV + i * 48 + p] = a;
  } else if (tid < 144) {
    int f2 = tid - 80;
    const float* Wn = wns + 64 * 64;               // wns[1]
    float a = 0;
    for (int f = 0; f < 64; ++f) a = fmaf(hsn[f], Wn[f * 64 + f2], a);
    hs1s[f2] = a;
  } else if (tid < 208) {
    int s = tid - 144, wv = s >> 2, c = s & 3;
    float a = 0;
    if (c < 3) {
      const float* Wn = wnv + 16 * 16;             // wnv[1]
      for (int v = 0; v < 16; ++v) a = fmaf(hvns[v][c], Wn[v * 16 + wv], a);
    }
    hv1s[wv][c] = a;
  }
  __syncthreads();
  if (tid < 16) {                                  // pack h_s^1 -> bf16x4
    uint2* HSB = (uint2*)(ws + WS_HSB);
    unsigned u0 = (unsigned)f2bf(hs1s[4 * tid + 0]) | ((unsigned)f2bf(hs1s[4 * tid + 1]) << 16);
    unsigned u1 = (unsigned)f2bf(hs1s[4 * tid + 2]) | ((unsigned)f2bf(hs1s[4 * tid + 3]) << 16);
    HSB[i * 16 + tid] = make_uint2(u0, u1);
  } else if (tid < 32) {                           // pack h_v^1 -> bf16 (x,y,z,0)
    int v = tid - 16;
    uint2* HVB = (uint2*)(ws + WS_HVB);
    unsigned u0 = (unsigned)f2bf(hv1s[v][0]) | ((unsigned)f2bf(hv1s[v][1]) << 16);
    unsigned u1 = (unsigned)f2bf(hv1s[v][2]);
    HVB[i * 16 + v] = make_uint2(u0, u1);
  }
}

// ------------------------------------------------------------- edge t=1 -----
__global__ __launch_bounds__(256) void k_edge1(float* __restrict__ ws) {
  const int blk = blockIdx.x, i = blk >> 2, part = blk & 3;
  const int tid = threadIdx.x;
  const int w = tid >> 6, lane = tid & 63, sq = (lane >> 4) & 3, idx = lane & 15;
  __shared__ float4 GEO[192];
  __shared__ float wb[4][16][25];    // odd stride: conflict-free
  const float4* XP4 = (const float4*)(ws + WS_XP);
  const uint4* T4 = (const uint4*)((unsigned*)(ws + WS_TBL) + 2049 * ROWC);  // t=1
  const uint2* HSB = (const uint2*)(ws + WS_HSB);
  const uint2* HVB = (const uint2*)(ws + WS_HVB);
  const float4 xi = XP4[i];
  if (tid < 192) {
    int j = part * 192 + tid;
    float4 xj = XP4[j];
    float dx = xi.x - xj.x, dy = xi.y - xj.y, dz = xi.z - xj.z;
    float r2 = dx * dx + dy * dy + dz * dz;
    float u, hx, hy, hz;
    if (j == i || r2 <= 0.0f) { u = 2048.0f; hx = hy = hz = 0.0f; }
    else {
      float rinv = rsqrtf(r2);
      hx = dx * rinv; hy = dy * rinv; hz = dz * rinv;
      u = fminf(r2 * rinv * SCALE, 2048.0f);
    }
    GEO[tid] = make_float4(hx, hy, hz, u);
  }
  __syncthreads();
  float s1[4] = {0, 0, 0, 0};
  float v1[4][3] = {};
  float s2 = 0, v2x = 0, v2y = 0, v2z = 0, v3x = 0, v3y = 0, v3z = 0;
  const int jbase = part * 192;
  for (int q = 0; q < 12; ++q) {
    int jl = w * 48 + q * 4 + sq;
    float4 g = GEO[jl];
    int i0 = (int)g.w;
    float fr = g.w - (float)i0;
    const uint4* rp = T4 + i0 * 48;
    uint4 t1 = rp[idx];
    uint4 t3 = rp[16 + idx];
    uint4 tv = rp[32 + idx];
    int jg = jbase + jl;
    uint2 esb = HSB[jg * 16 + idx];
    uint2 evb = HVB[jg * 16 + idx];
    float esx = bl(esb.x), esy = bh(esb.x), esz = bl(esb.y), esw = bh(esb.y);
    float evx = bl(evb.x), evy = bh(evb.x), evz = bl(evb.y);
    s1[0] += esx * lp(t1.x, fr); s1[1] += esy * lp(t1.y, fr);
    s1[2] += esz * lp(t1.z, fr); s1[3] += esw * lp(t1.w, fr);
    float ax = esx * lp(t3.x, fr), ay = esy * lp(t3.y, fr);
    float az = esz * lp(t3.z, fr), aw = esw * lp(t3.w, fr);
    v1[0][0] += ax * g.x; v1[0][1] += ax * g.y; v1[0][2] += ax * g.z;
    v1[1][0] += ay * g.x; v1[1][1] += ay * g.y; v1[1][2] += ay * g.z;
    v1[2][0] += az * g.x; v1[2][1] += az * g.y; v1[2][2] += az * g.z;
    v1[3][0] += aw * g.x; v1[3][1] += aw * g.y; v1[3][2] += aw * g.z;
    float rr2 = lp(tv.x, fr), rr4 = lp(tv.y, fr), rr5 = lp(tv.z, fr);
    float dt = evx * g.x + evy * g.y + evz * g.z;
    s2 += dt * rr2;
    v2x += evx * rr4; v2y += evy * rr4; v2z += evz * rr4;
    v3x += (evy * g.z - evz * g.y) * rr5;
    v3y += (evz * g.x - evx * g.z) * rr5;
    v3z += (evx * g.y - evy * g.x) * rr5;
  }
  float vals[23] = {s1[0], s1[1], s1[2], s1[3],
                    v1[0][0], v1[0][1], v1[0][2], v1[1][0], v1[1][1], v1[1][2],
                    v1[2][0], v1[2][1], v1[2][2], v1[3][0], v1[3][1], v1[3][2],
                    s2, v2x, v2y, v2z, v3x, v3y, v3z};
#pragma unroll
  for (int k = 0; k < 23; ++k) {
    float v = vals[k];
    v += __shfl_xor(v, 16);
    v += __shfl_xor(v, 32);
    if (lane < 16) wb[w][lane][k] = v;
  }
  __syncthreads();
  for (int s = tid; s < 368; s += 256) {
    int l, sl;
    if (s < 64) { l = s >> 2; sl = s & 3; }
    else if (s < 80) { l = s - 64; sl = 16; }
    else if (s < 272) { int p = s - 80, f = p / 3, c = p - 3 * f; l = f >> 2; sl = 4 + 3 * (f & 3) + c; }
    else if (s < 320) { int p = s - 272, v = p / 3, c = p - 3 * v; l = v; sl = 17 + c; }
    else { int p = s - 320, v = p / 3, c = p - 3 * v; l = v; sl = 20 + c; }
    ws[WS_SLAB1 + (part * Nn + i) * 384 + s] =
        wb[0][l][sl] + wb[1][l][sl] + wb[2][l][sl] + wb[3][l][sl];
  }
}

// ------------------------------------------------------------- post t=1 -----
__global__ __launch_bounds__(256) void k_post1(const float* __restrict__ wmixs,
                                               const float* __restrict__ wmixv,
                                               const float* __restrict__ wgate,
                                               const float* __restrict__ wros,
                                               const float* __restrict__ wrov,
                                               float* __restrict__ ws,
                                               float* __restrict__ out) {
  const int i = blockIdx.x, tid = threadIdx.x;
  __shared__ float agg[368];
  __shared__ float ms[64], mvv[16][3], gate[16], hsn[64], hvns[16][4];
  const float inv = 1.0f / AVGF;
  const float* S = ws + WS_SLAB1 + i * 384;
  for (int s = tid; s < 368; s += 256)
    agg[s] = (S[s] + S[Nn * 384 + s] + S[2 * Nn * 384 + s] + S[3 * Nn * 384 + s]) * inv;
  __syncthreads();
  if (tid < 64) {
    const float* Wm = wmixs + 80 * 64;             // wmixs[1]
    float a = 0;
    for (int p = 0; p < 80; ++p) a = fmaf(agg[p], Wm[p * 64 + tid], a);
    ms[tid] = a;
  } else if (tid < 112) {
    int c = (tid - 64) >> 4, v = (tid - 64) & 15;
    const float* Wv = wmixv + 96 * 16;             // wmixv[1]
    float a = 0;
    for (int p = 0; p < 96; ++p) {
      int ai = (p < 64) ? (80 + p * 3 + c) : (p < 80 ? (272 + (p - 64) * 3 + c)
                                                     : (320 + (p - 80) * 3 + c));
      a = fmaf(agg[ai], Wv[p * 16 + v], a);
    }
    mvv[v][c] = a;
  }
  __syncthreads();
  if (tid < 64) {
    float m = ms[tid];
    hsn[tid] = m / (1.0f + expf(-m));
  } else if (tid < 80) {
    int v = tid - 64;
    const float* Wg = wgate + 64 * 16;             // wgate[1]
    float a = 0;
    for (int f = 0; f < 64; ++f) a = fmaf(ms[f], Wg[f * 16 + v], a);
    gate[v] = 1.0f / (1.0f + expf(-a));
  }
  __syncthreads();
  if (tid < 64) {
    int v = tid >> 2, c = tid & 3;
    hvns[v][c] = (c < 3) ? gate[v] * mvv[v][c] : 0.0f;
  }
  __syncthreads();
  if (tid < 32) {
    const float* Wr = wros + 64 * 32;              // wros[1]
    float a = ws[WS_OS + i * 32 + tid];
    for (int f = 0; f < 64; ++f) a = fmaf(hsn[f], Wr[f * 32 + tid], a);
    out[i * 32 + tid] = a;
  } else if (tid < 80) {
    int p = tid - 32, k = p / 3, c = p - 3 * k;
    const float* Wr = wrov + 16 * 16;              // wrov[1]
    float a = ws[WS_OV + i * 48 + p] + ws[WS_COM + c];
    for (int v = 0; v < 16; ++v) a = fmaf(hvns[v][c], Wr[v * 16 + k], a);
    out[Nn * 32 + i * 48 + p] = a;
  }
}

// ------------------------------------------------------------- launch -------
extern "C" void kernel_launch(void* const* d_in, const int* in_sizes, int n_in,
                              void* d_out, int out_size, void* d_ws, size_t ws_size,
                              hipStream_t stream) {
  const float* x     = (const float*)d_in[0];
  const float* embed = (const float*)d_in[1];
  const float* wns   = (const float*)d_in[2];
  const float* wnv   = (const float*)d_in[3];
  const float* w1    = (const float*)d_in[4];
  const float* b1    = (const float*)d_in[5];
  const float* w2    = (const float*)d_in[6];
  const float* wmixs = (const float*)d_in[7];
  const float* wmixv = (const float*)d_in[8];
  const float* wgate = (const float*)d_in[9];
  const float* wros  = (const float*)d_in[10];
  const float* wrov  = (const float*)d_in[11];
  float* ws = (float*)d_ws;
  float* out = (float*)d_out;

  hipLaunchKernelGGL(k_setup, dim3(515),    dim3(256), 0, stream, x, embed, wns, w1, b1, w2, ws);
  hipLaunchKernelGGL(k_edge0, dim3(Nn * 4), dim3(256), 0, stream, ws);
  hipLaunchKernelGGL(k_post0, dim3(Nn),     dim3(256), 0, stream,
                     wns, wnv, wmixs, wmixv, wgate, wros, wrov, ws);
  hipLaunchKernelGGL(k_edge1, dim3(Nn * 4), dim3(256), 0, stream, ws);
  hipLaunchKernelGGL(k_post1, dim3(Nn),     dim3(256), 0, stream,
                     wmixs, wmixv, wgate, wros, wrov, ws, out);
}

// Round 6
// 154.890 us; speedup vs baseline: 1.7540x; 1.0029x over previous
//
#include <hip/hip_runtime.h>
#include <hip/hip_bf16.h>
#include <math.h>

#define Nn 768
#define Ff 64
#define Vv 16
#define NBb 8
#define HRr 64
#define Pp 176
#define TBL 1024
#define ROWC 176              // table cols per row: r1[64] r3[64] r2[16] r4[16] r5[16]
#define RMAXF 10.0f
#define AVGF 767.0f
#define SCALE 102.4f          // TBL / RMAX

// workspace float offsets
#define WS_COM   0
#define WS_ES0   16
#define WS_XP    128          // 768 x float4
#define WS_HSB   4096         // uint2[768][16]  : h_s^1 packed bf16 (4/uint2)
#define WS_HVB   28672        // uint2[768][16]  : h_v^1 packed bf16 (x,y,z,0)
#define WS_OS    53248        // [768][32] layer-0 scalar readout
#define WS_OV    77824        // [768][48] layer-0 vector readout ([k][c])
#define WS_SLAB0 131072       // float[4][768][256]
#define WS_SLAB1 917504       // float[4][768][384] (368 used)
#define WS_TBL   2097152      // unsigned[2][1025][176]: packed bf16 pairs (row,row+1)

__device__ __forceinline__ unsigned short f2bf(float f) {
  unsigned b = __float_as_uint(f);
  return (unsigned short)((b + 0x7fffu + ((b >> 16) & 1u)) >> 16);
}
__device__ __forceinline__ float lp(unsigned u, float f) {   // lerp packed pair
  float a = __uint_as_float(u << 16);
  float b = __uint_as_float(u & 0xffff0000u);
  return fmaf(f, b - a, a);
}
__device__ __forceinline__ float bl(unsigned u) { return __uint_as_float(u << 16); }
__device__ __forceinline__ float bh(unsigned u) { return __uint_as_float(u & 0xffff0000u); }

// ---------------------------------------------------------------- setup -----
// blocks 0..255: radial tables (t = b>>7, pair-rows (b&127)*8 ..+7)
// block 256: center of mass; 257: padded positions; 258: es0 = embed @ wns[0]
__global__ __launch_bounds__(256) void k_setup(const float* __restrict__ x,
                                               const float* __restrict__ embed,
                                               const float* __restrict__ wns,
                                               const float* __restrict__ w1,
                                               const float* __restrict__ b1,
                                               const float* __restrict__ w2,
                                               float* __restrict__ ws) {
  const int b = blockIdx.x, tid = threadIdx.x;
  if (b >= 256) {
    if (b == 256) {
      __shared__ float red[256][3];
      float a0 = 0, a1 = 0, a2 = 0;
      for (int n = tid; n < Nn; n += 256) {
        a0 += x[n * 3 + 0]; a1 += x[n * 3 + 1]; a2 += x[n * 3 + 2];
      }
      red[tid][0] = a0; red[tid][1] = a1; red[tid][2] = a2;
      __syncthreads();
      if (tid < 3) {
        float a = 0;
        for (int k = 0; k < 256; ++k) a += red[k][tid];
        ws[WS_COM + tid] = a * (1.0f / Nn);
      }
    } else if (b == 257) {
      for (int n = tid; n < Nn; n += 256) {
        ws[WS_XP + n * 4 + 0] = x[n * 3 + 0];
        ws[WS_XP + n * 4 + 1] = x[n * 3 + 1];
        ws[WS_XP + n * 4 + 2] = x[n * 3 + 2];
        ws[WS_XP + n * 4 + 3] = 0.0f;
      }
    } else {
      if (tid < 64) {
        float a = 0;
        for (int k = 0; k < 64; ++k) a = fmaf(embed[k], wns[k * 64 + tid], a);
        ws[WS_ES0 + tid] = a;
      }
    }
    return;
  }
  // ---- table block
  __shared__ float w2s[64][Pp];
  __shared__ float w1s[NBb][64];
  __shared__ float b1s[64];
  __shared__ float hid[9][65];
  const int t = b >> 7;
  const int r0 = (b & 127) * 8;
  const float* W2 = w2 + t * HRr * Pp;
  for (int k = tid; k < 64 * Pp; k += 256) w2s[k / Pp][k % Pp] = W2[k];
  for (int k = tid; k < NBb * 64; k += 256) w1s[k >> 6][k & 63] = w1[t * NBb * 64 + k];
  if (tid < 64) b1s[tid] = b1[t * 64 + tid];
  __syncthreads();
  {
    int rl4 = tid >> 6, h = tid & 63;
    const float c0 = 0.447213595f;               // sqrt(2/RMAX)
    const float pif = 3.14159265358979f;
    for (int pass = 0; pass < 3; ++pass) {
      int row_l = pass * 4 + rl4;
      if (row_l < 9) {
        int row = r0 + row_l;
        float r = row * (RMAXF / TBL);
        float acc = b1s[h];
        if (row == 0) {
          for (int n = 0; n < NBb; ++n) acc = fmaf(c0 * (n + 1) * (pif / RMAXF), w1s[n][h], acc);
        } else {
          float inv = 1.0f / r;
          for (int n = 0; n < NBb; ++n)
            acc = fmaf(c0 * sinf((n + 1) * pif * r / RMAXF) * inv, w1s[n][h], acc);
        }
        hid[row_l][h] = acc / (1.0f + expf(-acc));
      }
    }
  }
  __syncthreads();
  unsigned* T = (unsigned*)(ws + WS_TBL) + t * 1025 * ROWC;
  const int rl = tid & 7, colg = tid >> 3;       // 32 colgs x 6 cols (>=176 skipped)
  const int rowa = r0 + rl;
  float ra = rowa * (RMAXF / TBL), rb = (rowa + 1) * (RMAXF / TBL);
  float ua = 2.0f * (1.0f - ra / RMAXF), ub = 2.0f * (1.0f - rb / RMAXF);
  float env_a = (ua > 0.0f) ? 1.2f * expf(-1.0f / ua) : 0.0f;
  float env_b = (ub > 0.0f) ? 1.2f * expf(-1.0f / ub) : 0.0f;
  float accA[6], accB[6];
  int pcol[6]; bool vc[6];
#pragma unroll
  for (int c = 0; c < 6; ++c) {
    int col = colg * 6 + c;
    bool valid = (col < 176);
    int p = 0;
    if (valid) {
      if (col < 64) p = col;                       // r1 <- R[:, 0:64]
      else if (col < 128) p = 80 + (col - 64);     // r3 <- R[:, 80:144]
      else if (col < 144) p = 64 + (col - 128);    // r2 <- R[:, 64:80]
      else p = col;                                // r4 <- R[:,144:160], r5 <- R[:,160:176]
    }
    pcol[c] = p; vc[c] = valid; accA[c] = 0.0f; accB[c] = 0.0f;
  }
  for (int h = 0; h < 64; ++h) {
    float ha = hid[rl][h], hb = hid[rl + 1][h];
#pragma unroll
    for (int c = 0; c < 6; ++c) {
      float w = w2s[h][pcol[c]];
      accA[c] = fmaf(ha, w, accA[c]);
      accB[c] = fmaf(hb, w, accB[c]);
    }
  }
#pragma unroll
  for (int c = 0; c < 6; ++c) {
    if (vc[c]) {
      int col = colg * 6 + c;
      float va = accA[c] * env_a;
      float vb = accB[c] * env_b;
      T[rowa * ROWC + col] = ((unsigned)f2bf(vb) << 16) | (unsigned)f2bf(va);
    }
  }
  if ((b & 127) == 127) {                        // zero row 1024 (self / r>=RMAX)
    for (int k = tid; k < ROWC; k += 256) T[1024 * ROWC + k] = 0u;
  }
}

// ------------------------------------------------------------- edge t=0 -----
// 3072 blocks (4 parts/receiver). Only r1/r3 columns (es uniform, ev=0).
// Partial sums -> private slab (no atomics).
__global__ __launch_bounds__(256) void k_edge0(float* __restrict__ ws) {
  const int blk = blockIdx.x, i = blk >> 2, part = blk & 3;
  const int tid = threadIdx.x;
  const int w = tid >> 6, lane = tid & 63, sq = (lane >> 4) & 3, idx = lane & 15;
  __shared__ float4 GEO[192];
  __shared__ float wb[4][16][17];    // odd stride: conflict-free
  const float4* XP4 = (const float4*)(ws + WS_XP);
  const unsigned* T0 = (const unsigned*)(ws + WS_TBL);
  const float4 xi = XP4[i];
  if (tid < 192) {
    int j = part * 192 + tid;
    float4 xj = XP4[j];
    float dx = xi.x - xj.x, dy = xi.y - xj.y, dz = xi.z - xj.z;
    float r2 = dx * dx + dy * dy + dz * dz;
    float u, hx, hy, hz;
    if (j == i || r2 <= 0.0f) { u = 1024.0f; hx = hy = hz = 0.0f; }
    else {
      float rinv = rsqrtf(r2);
      hx = dx * rinv; hy = dy * rinv; hz = dz * rinv;
      u = fminf(r2 * rinv * SCALE, 1024.0f);
    }
    GEO[tid] = make_float4(hx, hy, hz, u);
  }
  __syncthreads();
  float s1[4] = {0, 0, 0, 0};
  float v1[4][3] = {};
  for (int q = 0; q < 12; ++q) {
    int jl = w * 48 + q * 4 + sq;
    float4 g = GEO[jl];
    int i0 = (int)g.w;
    float fr = g.w - (float)i0;
    const unsigned* row = T0 + i0 * ROWC;
    uint4 t1 = ((const uint4*)row)[idx];
    uint4 t3 = ((const uint4*)row)[16 + idx];
    s1[0] += lp(t1.x, fr); s1[1] += lp(t1.y, fr);
    s1[2] += lp(t1.z, fr); s1[3] += lp(t1.w, fr);
    float ax = lp(t3.x, fr), ay = lp(t3.y, fr), az = lp(t3.z, fr), aw = lp(t3.w, fr);
    v1[0][0] += ax * g.x; v1[0][1] += ax * g.y; v1[0][2] += ax * g.z;
    v1[1][0] += ay * g.x; v1[1][1] += ay * g.y; v1[1][2] += ay * g.z;
    v1[2][0] += az * g.x; v1[2][1] += az * g.y; v1[2][2] += az * g.z;
    v1[3][0] += aw * g.x; v1[3][1] += aw * g.y; v1[3][2] += aw * g.z;
  }
  float vals[16] = {s1[0], s1[1], s1[2], s1[3],
                    v1[0][0], v1[0][1], v1[0][2], v1[1][0], v1[1][1], v1[1][2],
                    v1[2][0], v1[2][1], v1[2][2], v1[3][0], v1[3][1], v1[3][2]};
#pragma unroll
  for (int k = 0; k < 16; ++k) {
    float v = vals[k];
    v += __shfl_xor(v, 16);
    v += __shfl_xor(v, 32);
    if (lane < 16) wb[w][lane][k] = v;
  }
  __syncthreads();
  {
    int l, s;
    if (tid < 64) { l = tid >> 2; s = tid & 3; }
    else { int p = tid - 64, f = p / 3, c = p - 3 * f; l = f >> 2; s = 4 + 3 * (f & 3) + c; }
    float a = wb[0][l][s] + wb[1][l][s] + wb[2][l][s] + wb[3][l][s];
    ws[WS_SLAB0 + (part * Nn + i) * 256 + tid] = a;
  }
}

// ------------------------------------------------------------- post t=0 -----
// Sum slabs, apply es0, node update, layer-0 readout, layer-1 node transforms
// packed to bf16 for k_edge1.
__global__ __launch_bounds__(256) void k_post0(const float* __restrict__ wns,
                                               const float* __restrict__ wnv,
                                               const float* __restrict__ wmixs,
                                               const float* __restrict__ wmixv,
                                               const float* __restrict__ wgate,
                                               const float* __restrict__ wros,
                                               const float* __restrict__ wrov,
                                               float* __restrict__ ws) {
  const int i = blockIdx.x, tid = threadIdx.x;
  __shared__ float agg[256];
  __shared__ float ms[64], mvv[16][3], gate[16], hsn[64], hvns[16][4];
  __shared__ float hs1s[64], hv1s[16][4];
  const float inv = 1.0f / AVGF;
  const float* S = ws + WS_SLAB0 + i * 256;
  {
    float a = S[tid] + S[Nn * 256 + tid] + S[2 * Nn * 256 + tid] + S[3 * Nn * 256 + tid];
    float es0f = (tid < 64) ? ws[WS_ES0 + tid] : ws[WS_ES0 + (tid - 64) / 3];
    agg[tid] = a * inv * es0f;
  }
  __syncthreads();
  if (tid < 64) {                    // dot-slots of wmixs rows 64..79 are 0 at t=0
    const float* Wm = wmixs;
    float a = 0;
    for (int p = 0; p < 64; ++p) a = fmaf(agg[p], Wm[p * 64 + tid], a);
    ms[tid] = a;
  } else if (tid < 112) {            // v2/v3 rows of wmixv are 0 at t=0
    int c = (tid - 64) >> 4, v = (tid - 64) & 15;
    const float* Wv = wmixv;
    float a = 0;
    for (int p = 0; p < 64; ++p) a = fmaf(agg[64 + p * 3 + c], Wv[p * 16 + v], a);
    mvv[v][c] = a;
  }
  __syncthreads();
  if (tid < 64) {
    float m = ms[tid];
    hsn[tid] = m / (1.0f + expf(-m));
  } else if (tid < 80) {
    int v = tid - 64;
    float a = 0;
    for (int f = 0; f < 64; ++f) a = fmaf(ms[f], wgate[f * 16 + v], a);
    gate[v] = 1.0f / (1.0f + expf(-a));
  }
  __syncthreads();
  if (tid < 64) {
    int v = tid >> 2, c = tid & 3;
    hvns[v][c] = (c < 3) ? gate[v] * mvv[v][c] : 0.0f;
  }
  __syncthreads();
  if (tid < 32) {
    float a = 0;
    for (int f = 0; f < 64; ++f) a = fmaf(hsn[f], wros[f * 32 + tid], a);
    ws[WS_OS + i * 32 + tid] = a;
  } else if (tid < 80) {
    int p = tid - 32, k = p / 3, c = p - 3 * k;
    float a = 0;
    for (int v = 0; v < 16; ++v) a = fmaf(hvns[v][c], wrov[v * 16 + k], a);
    ws[WS_OV + i * 48 + p] = a;
  } else if (tid < 144) {
    int f2 = tid - 80;
    const float* Wn = wns + 64 * 64;               // wns[1]
    float a = 0;
    for (int f = 0; f < 64; ++f) a = fmaf(hsn[f], Wn[f * 64 + f2], a);
    hs1s[f2] = a;
  } else if (tid < 208) {
    int s = tid - 144, wv = s >> 2, c = s & 3;
    float a = 0;
    if (c < 3) {
      const float* Wn = wnv + 16 * 16;             // wnv[1]
      for (int v = 0; v < 16; ++v) a = fmaf(hvns[v][c], Wn[v * 16 + wv], a);
    }
    hv1s[wv][c] = a;
  }
  __syncthreads();
  if (tid < 16) {                                  // pack h_s^1 -> bf16x4
    uint2* HSB = (uint2*)(ws + WS_HSB);
    unsigned u0 = (unsigned)f2bf(hs1s[4 * tid + 0]) | ((unsigned)f2bf(hs1s[4 * tid + 1]) << 16);
    unsigned u1 = (unsigned)f2bf(hs1s[4 * tid + 2]) | ((unsigned)f2bf(hs1s[4 * tid + 3]) << 16);
    HSB[i * 16 + tid] = make_uint2(u0, u1);
  } else if (tid < 32) {                           // pack h_v^1 -> bf16 (x,y,z,0)
    int v = tid - 16;
    uint2* HVB = (uint2*)(ws + WS_HVB);
    unsigned u0 = (unsigned)f2bf(hv1s[v][0]) | ((unsigned)f2bf(hv1s[v][1]) << 16);
    unsigned u1 = (unsigned)f2bf(hv1s[v][2]);
    HVB[i * 16 + v] = make_uint2(u0, u1);
  }
}

// ------------------------------------------------------------- edge t=1 -----
__global__ __launch_bounds__(256) void k_edge1(float* __restrict__ ws) {
  const int blk = blockIdx.x, i = blk >> 2, part = blk & 3;
  const int tid = threadIdx.x;
  const int w = tid >> 6, lane = tid & 63, sq = (lane >> 4) & 3, idx = lane & 15;
  __shared__ float4 GEO[192];
  __shared__ float wb[4][16][25];    // odd stride: conflict-free
  const float4* XP4 = (const float4*)(ws + WS_XP);
  const unsigned* T1 = (const unsigned*)(ws + WS_TBL) + 1025 * ROWC;  // t=1
  const uint2* HSB = (const uint2*)(ws + WS_HSB);
  const uint2* HVB = (const uint2*)(ws + WS_HVB);
  const float4 xi = XP4[i];
  if (tid < 192) {
    int j = part * 192 + tid;
    float4 xj = XP4[j];
    float dx = xi.x - xj.x, dy = xi.y - xj.y, dz = xi.z - xj.z;
    float r2 = dx * dx + dy * dy + dz * dz;
    float u, hx, hy, hz;
    if (j == i || r2 <= 0.0f) { u = 1024.0f; hx = hy = hz = 0.0f; }
    else {
      float rinv = rsqrtf(r2);
      hx = dx * rinv; hy = dy * rinv; hz = dz * rinv;
      u = fminf(r2 * rinv * SCALE, 1024.0f);
    }
    GEO[tid] = make_float4(hx, hy, hz, u);
  }
  __syncthreads();
  float s1[4] = {0, 0, 0, 0};
  float v1[4][3] = {};
  float s2 = 0, v2x = 0, v2y = 0, v2z = 0, v3x = 0, v3y = 0, v3z = 0;
  const int jbase = part * 192;
  for (int q = 0; q < 12; ++q) {
    int jl = w * 48 + q * 4 + sq;
    float4 g = GEO[jl];
    int i0 = (int)g.w;
    float fr = g.w - (float)i0;
    const unsigned* row = T1 + i0 * ROWC;
    uint4 t1 = ((const uint4*)row)[idx];
    uint4 t3 = ((const uint4*)row)[16 + idx];
    unsigned u2 = row[128 + idx];
    unsigned u4 = row[144 + idx];
    unsigned u5 = row[160 + idx];
    int jg = jbase + jl;
    uint2 esb = HSB[jg * 16 + idx];
    uint2 evb = HVB[jg * 16 + idx];
    float esx = bl(esb.x), esy = bh(esb.x), esz = bl(esb.y), esw = bh(esb.y);
    float evx = bl(evb.x), evy = bh(evb.x), evz = bl(evb.y);
    s1[0] += esx * lp(t1.x, fr); s1[1] += esy * lp(t1.y, fr);
    s1[2] += esz * lp(t1.z, fr); s1[3] += esw * lp(t1.w, fr);
    float ax = esx * lp(t3.x, fr), ay = esy * lp(t3.y, fr);
    float az = esz * lp(t3.z, fr), aw = esw * lp(t3.w, fr);
    v1[0][0] += ax * g.x; v1[0][1] += ax * g.y; v1[0][2] += ax * g.z;
    v1[1][0] += ay * g.x; v1[1][1] += ay * g.y; v1[1][2] += ay * g.z;
    v1[2][0] += az * g.x; v1[2][1] += az * g.y; v1[2][2] += az * g.z;
    v1[3][0] += aw * g.x; v1[3][1] += aw * g.y; v1[3][2] += aw * g.z;
    float rr2 = lp(u2, fr), rr4 = lp(u4, fr), rr5 = lp(u5, fr);
    float dt = evx * g.x + evy * g.y + evz * g.z;
    s2 += dt * rr2;
    v2x += evx * rr4; v2y += evy * rr4; v2z += evz * rr4;
    v3x += (evy * g.z - evz * g.y) * rr5;
    v3y += (evz * g.x - evx * g.z) * rr5;
    v3z += (evx * g.y - evy * g.x) * rr5;
  }
  float vals[23] = {s1[0], s1[1], s1[2], s1[3],
                    v1[0][0], v1[0][1], v1[0][2], v1[1][0], v1[1][1], v1[1][2],
                    v1[2][0], v1[2][1], v1[2][2], v1[3][0], v1[3][1], v1[3][2],
                    s2, v2x, v2y, v2z, v3x, v3y, v3z};
#pragma unroll
  for (int k = 0; k < 23; ++k) {
    float v = vals[k];
    v += __shfl_xor(v, 16);
    v += __shfl_xor(v, 32);
    if (lane < 16) wb[w][lane][k] = v;
  }
  __syncthreads();
  for (int s = tid; s < 368; s += 256) {
    int l, sl;
    if (s < 64) { l = s >> 2; sl = s & 3; }
    else if (s < 80) { l = s - 64; sl = 16; }
    else if (s < 272) { int p = s - 80, f = p / 3, c = p - 3 * f; l = f >> 2; sl = 4 + 3 * (f & 3) + c; }
    else if (s < 320) { int p = s - 272, v = p / 3, c = p - 3 * v; l = v; sl = 17 + c; }
    else { int p = s - 320, v = p / 3, c = p - 3 * v; l = v; sl = 20 + c; }
    ws[WS_SLAB1 + (part * Nn + i) * 384 + s] =
        wb[0][l][sl] + wb[1][l][sl] + wb[2][l][sl] + wb[3][l][sl];
  }
}

// ------------------------------------------------------------- post t=1 -----
__global__ __launch_bounds__(256) void k_post1(const float* __restrict__ wmixs,
                                               const float* __restrict__ wmixv,
                                               const float* __restrict__ wgate,
                                               const float* __restrict__ wros,
                                               const float* __restrict__ wrov,
                                               float* __restrict__ ws,
                                               float* __restrict__ out) {
  const int i = blockIdx.x, tid = threadIdx.x;
  __shared__ float agg[368];
  __shared__ float ms[64], mvv[16][3], gate[16], hsn[64], hvns[16][4];
  const float inv = 1.0f / AVGF;
  const float* S = ws + WS_SLAB1 + i * 384;
  for (int s = tid; s < 368; s += 256)
    agg[s] = (S[s] + S[Nn * 384 + s] + S[2 * Nn * 384 + s] + S[3 * Nn * 384 + s]) * inv;
  __syncthreads();
  if (tid < 64) {
    const float* Wm = wmixs + 80 * 64;             // wmixs[1]
    float a = 0;
    for (int p = 0; p < 80; ++p) a = fmaf(agg[p], Wm[p * 64 + tid], a);
    ms[tid] = a;
  } else if (tid < 112) {
    int c = (tid - 64) >> 4, v = (tid - 64) & 15;
    const float* Wv = wmixv + 96 * 16;             // wmixv[1]
    float a = 0;
    for (int p = 0; p < 96; ++p) {
      int ai = (p < 64) ? (80 + p * 3 + c) : (p < 80 ? (272 + (p - 64) * 3 + c)
                                                     : (320 + (p - 80) * 3 + c));
      a = fmaf(agg[ai], Wv[p * 16 + v], a);
    }
    mvv[v][c] = a;
  }
  __syncthreads();
  if (tid < 64) {
    float m = ms[tid];
    hsn[tid] = m / (1.0f + expf(-m));
  } else if (tid < 80) {
    int v = tid - 64;
    const float* Wg = wgate + 64 * 16;             // wgate[1]
    float a = 0;
    for (int f = 0; f < 64; ++f) a = fmaf(ms[f], Wg[f * 16 + v], a);
    gate[v] = 1.0f / (1.0f + expf(-a));
  }
  __syncthreads();
  if (tid < 64) {
    int v = tid >> 2, c = tid & 3;
    hvns[v][c] = (c < 3) ? gate[v] * mvv[v][c] : 0.0f;
  }
  __syncthreads();
  if (tid < 32) {
    const float* Wr = wros + 64 * 32;              // wros[1]
    float a = ws[WS_OS + i * 32 + tid];
    for (int f = 0; f < 64; ++f) a = fmaf(hsn[f], Wr[f * 32 + tid], a);
    out[i * 32 + tid] = a;
  } else if (tid < 80) {
    int p = tid - 32, k = p / 3, c = p - 3 * k;
    const float* Wr = wrov + 16 * 16;              // wrov[1]
    float a = ws[WS_OV + i * 48 + p] + ws[WS_COM + c];
    for (int v = 0; v < 16; ++v) a = fmaf(hvns[v][c], Wr[v * 16 + k], a);
    out[Nn * 32 + i * 48 + p] = a;
  }
}

// ------------------------------------------------------------- launch -------
extern "C" void kernel_launch(void* const* d_in, const int* in_sizes, int n_in,
                              void* d_out, int out_size, void* d_ws, size_t ws_size,
                              hipStream_t stream) {
  const float* x     = (const float*)d_in[0];
  const float* embed = (const float*)d_in[1];
  const float* wns   = (const float*)d_in[2];
  const float* wnv   = (const float*)d_in[3];
  const float* w1    = (const float*)d_in[4];
  const float* b1    = (const float*)d_in[5];
  const float* w2    = (const float*)d_in[6];
  const float* wmixs = (const float*)d_in[7];
  const float* wmixv = (const float*)d_in[8];
  const float* wgate = (const float*)d_in[9];
  const float* wros  = (const float*)d_in[10];
  const float* wrov  = (const float*)d_in[11];
  float* ws = (float*)d_ws;
  float* out = (float*)d_out;

  hipLaunchKernelGGL(k_setup, dim3(259),    dim3(256), 0, stream, x, embed, wns, w1, b1, w2, ws);
  hipLaunchKernelGGL(k_edge0, dim3(Nn * 4), dim3(256), 0, stream, ws);
  hipLaunchKernelGGL(k_post0, dim3(Nn),     dim3(256), 0, stream,
                     wns, wnv, wmixs, wmixv, wgate, wros, wrov, ws);
  hipLaunchKernelGGL(k_edge1, dim3(Nn * 4), dim3(256), 0, stream, ws);
  hipLaunchKernelGGL(k_post1, dim3(Nn),     dim3(256), 0, stream,
                     wmixs, wmixv, wgate, wros, wrov, ws, out);
}

// Round 7
// 151.610 us; speedup vs baseline: 1.7919x; 1.0216x over previous
//
#include <hip/hip_runtime.h>
#include <hip/hip_bf16.h>
#include <math.h>

#define Nn 768
#define Ff 64
#define Vv 16
#define NBb 8
#define HRr 64
#define Pp 176
#define TBL 1024
#define ROWC 176              // table cols per row: r1[64] r3[64] r2[16] r4[16] r5[16]
#define RMAXF 10.0f
#define AVGF 767.0f
#define SCALE 102.4f          // TBL / RMAX

// workspace float offsets
#define WS_COM   0
#define WS_ES0   16
#define WS_XP    128          // 768 x float4
#define WS_HSB   4096         // uint2[768][16]  : h_s^1 packed bf16 (4/uint2)
#define WS_HVB   28672        // uint2[768][16]  : h_v^1 packed bf16 (x,y,z,0)
#define WS_OS    53248        // [768][32] layer-0 scalar readout
#define WS_OV    77824        // [768][48] layer-0 vector readout ([k][c])
#define WS_SLAB0 131072       // float[4][768][256]
#define WS_SLAB1 917504       // float[4][768][384] (368 used)
#define WS_TBL   2097152      // unsigned[2][1025][176]: packed bf16 pairs (row,row+1)

__device__ __forceinline__ unsigned short f2bf(float f) {
  unsigned b = __float_as_uint(f);
  return (unsigned short)((b + 0x7fffu + ((b >> 16) & 1u)) >> 16);
}
__device__ __forceinline__ float lp(unsigned u, float f) {   // lerp packed pair
  float a = __uint_as_float(u << 16);
  float b = __uint_as_float(u & 0xffff0000u);
  return fmaf(f, b - a, a);
}
__device__ __forceinline__ float bl(unsigned u) { return __uint_as_float(u << 16); }
__device__ __forceinline__ float bh(unsigned u) { return __uint_as_float(u & 0xffff0000u); }

// ---------------------------------------------------------------- setup -----
// blocks 0..255: radial tables (t = b>>7, pair-rows (b&127)*8 ..+7)
// block 256: center of mass; 257: padded positions; 258: es0 = embed @ wns[0]
__global__ __launch_bounds__(256) void k_setup(const float* __restrict__ x,
                                               const float* __restrict__ embed,
                                               const float* __restrict__ wns,
                                               const float* __restrict__ w1,
                                               const float* __restrict__ b1,
                                               const float* __restrict__ w2,
                                               float* __restrict__ ws) {
  const int b = blockIdx.x, tid = threadIdx.x;
  if (b >= 256) {
    if (b == 256) {
      __shared__ float red[256][3];
      float a0 = 0, a1 = 0, a2 = 0;
      for (int n = tid; n < Nn; n += 256) {
        a0 += x[n * 3 + 0]; a1 += x[n * 3 + 1]; a2 += x[n * 3 + 2];
      }
      red[tid][0] = a0; red[tid][1] = a1; red[tid][2] = a2;
      __syncthreads();
      if (tid < 3) {
        float a = 0;
        for (int k = 0; k < 256; ++k) a += red[k][tid];
        ws[WS_COM + tid] = a * (1.0f / Nn);
      }
    } else if (b == 257) {
      for (int n = tid; n < Nn; n += 256) {
        ws[WS_XP + n * 4 + 0] = x[n * 3 + 0];
        ws[WS_XP + n * 4 + 1] = x[n * 3 + 1];
        ws[WS_XP + n * 4 + 2] = x[n * 3 + 2];
        ws[WS_XP + n * 4 + 3] = 0.0f;
      }
    } else {
      if (tid < 64) {
        float a = 0;
        for (int k = 0; k < 64; ++k) a = fmaf(embed[k], wns[k * 64 + tid], a);
        ws[WS_ES0 + tid] = a;
      }
    }
    return;
  }
  // ---- table block
  __shared__ float w2s[64][Pp];
  __shared__ float w1s[NBb][64];
  __shared__ float b1s[64];
  __shared__ float hid[9][65];
  const int t = b >> 7;
  const int r0 = (b & 127) * 8;
  const float* W2 = w2 + t * HRr * Pp;
  for (int k = tid; k < 64 * Pp; k += 256) w2s[k / Pp][k % Pp] = W2[k];
  for (int k = tid; k < NBb * 64; k += 256) w1s[k >> 6][k & 63] = w1[t * NBb * 64 + k];
  if (tid < 64) b1s[tid] = b1[t * 64 + tid];
  __syncthreads();
  {
    int rl4 = tid >> 6, h = tid & 63;
    const float c0 = 0.447213595f;               // sqrt(2/RMAX)
    const float pif = 3.14159265358979f;
    for (int pass = 0; pass < 3; ++pass) {
      int row_l = pass * 4 + rl4;
      if (row_l < 9) {
        int row = r0 + row_l;
        float r = row * (RMAXF / TBL);
        float acc = b1s[h];
        if (row == 0) {
          for (int n = 0; n < NBb; ++n) acc = fmaf(c0 * (n + 1) * (pif / RMAXF), w1s[n][h], acc);
        } else {
          float inv = 1.0f / r;
          for (int n = 0; n < NBb; ++n)
            acc = fmaf(c0 * sinf((n + 1) * pif * r / RMAXF) * inv, w1s[n][h], acc);
        }
        hid[row_l][h] = acc / (1.0f + expf(-acc));
      }
    }
  }
  __syncthreads();
  unsigned* T = (unsigned*)(ws + WS_TBL) + t * 1025 * ROWC;
  const int rl = tid & 7, colg = tid >> 3;       // 32 colgs x 6 cols (>=176 skipped)
  const int rowa = r0 + rl;
  float ra = rowa * (RMAXF / TBL), rb = (rowa + 1) * (RMAXF / TBL);
  float ua = 2.0f * (1.0f - ra / RMAXF), ub = 2.0f * (1.0f - rb / RMAXF);
  float env_a = (ua > 0.0f) ? 1.2f * expf(-1.0f / ua) : 0.0f;
  float env_b = (ub > 0.0f) ? 1.2f * expf(-1.0f / ub) : 0.0f;
  float accA[6], accB[6];
  int pcol[6]; bool vc[6];
#pragma unroll
  for (int c = 0; c < 6; ++c) {
    int col = colg * 6 + c;
    bool valid = (col < 176);
    int p = 0;
    if (valid) {
      if (col < 64) p = col;                       // r1 <- R[:, 0:64]
      else if (col < 128) p = 80 + (col - 64);     // r3 <- R[:, 80:144]
      else if (col < 144) p = 64 + (col - 128);    // r2 <- R[:, 64:80]
      else p = col;                                // r4 <- R[:,144:160], r5 <- R[:,160:176]
    }
    pcol[c] = p; vc[c] = valid; accA[c] = 0.0f; accB[c] = 0.0f;
  }
  for (int h = 0; h < 64; ++h) {
    float ha = hid[rl][h], hb = hid[rl + 1][h];
#pragma unroll
    for (int c = 0; c < 6; ++c) {
      float w = w2s[h][pcol[c]];
      accA[c] = fmaf(ha, w, accA[c]);
      accB[c] = fmaf(hb, w, accB[c]);
    }
  }
#pragma unroll
  for (int c = 0; c < 6; ++c) {
    if (vc[c]) {
      int col = colg * 6 + c;
      float va = accA[c] * env_a;
      float vb = accB[c] * env_b;
      T[rowa * ROWC + col] = ((unsigned)f2bf(vb) << 16) | (unsigned)f2bf(va);
    }
  }
  if ((b & 127) == 127) {                        // zero row 1024 (self / r>=RMAX)
    for (int k = tid; k < ROWC; k += 256) T[1024 * ROWC + k] = 0u;
  }
}

// ------------------------------------------------------------- edge t=0 -----
// 3072 blocks (4 parts/receiver). Only r1/r3 columns (es uniform, ev=0).
// Software-pipelined: iteration q+1's table loads issue before q's FMAs.
__global__ __launch_bounds__(256) void k_edge0(float* __restrict__ ws) {
  const int blk = blockIdx.x, i = blk >> 2, part = blk & 3;
  const int tid = threadIdx.x;
  const int w = tid >> 6, lane = tid & 63, sq = (lane >> 4) & 3, idx = lane & 15;
  __shared__ float4 GEO[192];
  __shared__ float wb[4][16][17];    // odd stride: conflict-free
  const float4* XP4 = (const float4*)(ws + WS_XP);
  const unsigned* T0 = (const unsigned*)(ws + WS_TBL);
  const float4 xi = XP4[i];
  if (tid < 192) {
    int j = part * 192 + tid;
    float4 xj = XP4[j];
    float dx = xi.x - xj.x, dy = xi.y - xj.y, dz = xi.z - xj.z;
    float r2 = dx * dx + dy * dy + dz * dz;
    float u, hx, hy, hz;
    if (j == i || r2 <= 0.0f) { u = 1024.0f; hx = hy = hz = 0.0f; }
    else {
      float rinv = rsqrtf(r2);
      hx = dx * rinv; hy = dy * rinv; hz = dz * rinv;
      u = fminf(r2 * rinv * SCALE, 1024.0f);
    }
    GEO[tid] = make_float4(hx, hy, hz, u);
  }
  __syncthreads();
  float s1[4] = {0, 0, 0, 0};
  float v1[4][3] = {};
  const int base = w * 48 + sq;
  // ---- pipeline prologue: load iter 0
  float4 g = GEO[base];
  int i0 = (int)g.w;
  float fr = g.w - (float)i0;
  const uint4* rp = (const uint4*)(T0 + i0 * ROWC);
  uint4 t1 = rp[idx];
  uint4 t3 = rp[16 + idx];
  for (int q = 0; q < 12; ++q) {
    // current stage registers
    float4 gc = g; float frc = fr;
    uint4 t1c = t1, t3c = t3;
    // prefetch next stage
    if (q < 11) {
      g = GEO[base + (q + 1) * 4];
      i0 = (int)g.w;
      fr = g.w - (float)i0;
      const uint4* rpn = (const uint4*)(T0 + i0 * ROWC);
      t1 = rpn[idx];
      t3 = rpn[16 + idx];
    }
    // compute with current
    s1[0] += lp(t1c.x, frc); s1[1] += lp(t1c.y, frc);
    s1[2] += lp(t1c.z, frc); s1[3] += lp(t1c.w, frc);
    float ax = lp(t3c.x, frc), ay = lp(t3c.y, frc), az = lp(t3c.z, frc), aw = lp(t3c.w, frc);
    v1[0][0] += ax * gc.x; v1[0][1] += ax * gc.y; v1[0][2] += ax * gc.z;
    v1[1][0] += ay * gc.x; v1[1][1] += ay * gc.y; v1[1][2] += ay * gc.z;
    v1[2][0] += az * gc.x; v1[2][1] += az * gc.y; v1[2][2] += az * gc.z;
    v1[3][0] += aw * gc.x; v1[3][1] += aw * gc.y; v1[3][2] += aw * gc.z;
  }
  float vals[16] = {s1[0], s1[1], s1[2], s1[3],
                    v1[0][0], v1[0][1], v1[0][2], v1[1][0], v1[1][1], v1[1][2],
                    v1[2][0], v1[2][1], v1[2][2], v1[3][0], v1[3][1], v1[3][2]};
#pragma unroll
  for (int k = 0; k < 16; ++k) {
    float v = vals[k];
    v += __shfl_xor(v, 16);
    v += __shfl_xor(v, 32);
    if (lane < 16) wb[w][lane][k] = v;
  }
  __syncthreads();
  {
    int l, s;
    if (tid < 64) { l = tid >> 2; s = tid & 3; }
    else { int p = tid - 64, f = p / 3, c = p - 3 * f; l = f >> 2; s = 4 + 3 * (f & 3) + c; }
    float a = wb[0][l][s] + wb[1][l][s] + wb[2][l][s] + wb[3][l][s];
    ws[WS_SLAB0 + (part * Nn + i) * 256 + tid] = a;
  }
}

// ------------------------------------------------------------- post t=0 -----
// Sum slabs, apply es0, node update, layer-0 readout, layer-1 node transforms
// packed to bf16 for k_edge1.
__global__ __launch_bounds__(256) void k_post0(const float* __restrict__ wns,
                                               const float* __restrict__ wnv,
                                               const float* __restrict__ wmixs,
                                               const float* __restrict__ wmixv,
                                               const float* __restrict__ wgate,
                                               const float* __restrict__ wros,
                                               const float* __restrict__ wrov,
                                               float* __restrict__ ws) {
  const int i = blockIdx.x, tid = threadIdx.x;
  __shared__ float agg[256];
  __shared__ float ms[64], mvv[16][3], gate[16], hsn[64], hvns[16][4];
  __shared__ float hs1s[64], hv1s[16][4];
  const float inv = 1.0f / AVGF;
  const float* S = ws + WS_SLAB0 + i * 256;
  {
    float a = S[tid] + S[Nn * 256 + tid] + S[2 * Nn * 256 + tid] + S[3 * Nn * 256 + tid];
    float es0f = (tid < 64) ? ws[WS_ES0 + tid] : ws[WS_ES0 + (tid - 64) / 3];
    agg[tid] = a * inv * es0f;
  }
  __syncthreads();
  if (tid < 64) {                    // dot-slots of wmixs rows 64..79 are 0 at t=0
    const float* Wm = wmixs;
    float a = 0;
    for (int p = 0; p < 64; ++p) a = fmaf(agg[p], Wm[p * 64 + tid], a);
    ms[tid] = a;
  } else if (tid < 112) {            // v2/v3 rows of wmixv are 0 at t=0
    int c = (tid - 64) >> 4, v = (tid - 64) & 15;
    const float* Wv = wmixv;
    float a = 0;
    for (int p = 0; p < 64; ++p) a = fmaf(agg[64 + p * 3 + c], Wv[p * 16 + v], a);
    mvv[v][c] = a;
  }
  __syncthreads();
  if (tid < 64) {
    float m = ms[tid];
    hsn[tid] = m / (1.0f + expf(-m));
  } else if (tid < 80) {
    int v = tid - 64;
    float a = 0;
    for (int f = 0; f < 64; ++f) a = fmaf(ms[f], wgate[f * 16 + v], a);
    gate[v] = 1.0f / (1.0f + expf(-a));
  }
  __syncthreads();
  if (tid < 64) {
    int v = tid >> 2, c = tid & 3;
    hvns[v][c] = (c < 3) ? gate[v] * mvv[v][c] : 0.0f;
  }
  __syncthreads();
  if (tid < 32) {
    float a = 0;
    for (int f = 0; f < 64; ++f) a = fmaf(hsn[f], wros[f * 32 + tid], a);
    ws[WS_OS + i * 32 + tid] = a;
  } else if (tid < 80) {
    int p = tid - 32, k = p / 3, c = p - 3 * k;
    float a = 0;
    for (int v = 0; v < 16; ++v) a = fmaf(hvns[v][c], wrov[v * 16 + k], a);
    ws[WS_OV + i * 48 + p] = a;
  } else if (tid < 144) {
    int f2 = tid - 80;
    const float* Wn = wns + 64 * 64;               // wns[1]
    float a = 0;
    for (int f = 0; f < 64; ++f) a = fmaf(hsn[f], Wn[f * 64 + f2], a);
    hs1s[f2] = a;
  } else if (tid < 208) {
    int s = tid - 144, wv = s >> 2, c = s & 3;
    float a = 0;
    if (c < 3) {
      const float* Wn = wnv + 16 * 16;             // wnv[1]
      for (int v = 0; v < 16; ++v) a = fmaf(hvns[v][c], Wn[v * 16 + wv], a);
    }
    hv1s[wv][c] = a;
  }
  __syncthreads();
  if (tid < 16) {                                  // pack h_s^1 -> bf16x4
    uint2* HSB = (uint2*)(ws + WS_HSB);
    unsigned u0 = (unsigned)f2bf(hs1s[4 * tid + 0]) | ((unsigned)f2bf(hs1s[4 * tid + 1]) << 16);
    unsigned u1 = (unsigned)f2bf(hs1s[4 * tid + 2]) | ((unsigned)f2bf(hs1s[4 * tid + 3]) << 16);
    HSB[i * 16 + tid] = make_uint2(u0, u1);
  } else if (tid < 32) {                           // pack h_v^1 -> bf16 (x,y,z,0)
    int v = tid - 16;
    uint2* HVB = (uint2*)(ws + WS_HVB);
    unsigned u0 = (unsigned)f2bf(hv1s[v][0]) | ((unsigned)f2bf(hv1s[v][1]) << 16);
    unsigned u1 = (unsigned)f2bf(hv1s[v][2]);
    HVB[i * 16 + v] = make_uint2(u0, u1);
  }
}

// ------------------------------------------------------------- edge t=1 -----
// Software-pipelined 1-deep like k_edge0.
__global__ __launch_bounds__(256) void k_edge1(float* __restrict__ ws) {
  const int blk = blockIdx.x, i = blk >> 2, part = blk & 3;
  const int tid = threadIdx.x;
  const int w = tid >> 6, lane = tid & 63, sq = (lane >> 4) & 3, idx = lane & 15;
  __shared__ float4 GEO[192];
  __shared__ float wb[4][16][25];    // odd stride: conflict-free
  const float4* XP4 = (const float4*)(ws + WS_XP);
  const unsigned* T1 = (const unsigned*)(ws + WS_TBL) + 1025 * ROWC;  // t=1
  const uint2* HSB = (const uint2*)(ws + WS_HSB);
  const uint2* HVB = (const uint2*)(ws + WS_HVB);
  const float4 xi = XP4[i];
  if (tid < 192) {
    int j = part * 192 + tid;
    float4 xj = XP4[j];
    float dx = xi.x - xj.x, dy = xi.y - xj.y, dz = xi.z - xj.z;
    float r2 = dx * dx + dy * dy + dz * dz;
    float u, hx, hy, hz;
    if (j == i || r2 <= 0.0f) { u = 1024.0f; hx = hy = hz = 0.0f; }
    else {
      float rinv = rsqrtf(r2);
      hx = dx * rinv; hy = dy * rinv; hz = dz * rinv;
      u = fminf(r2 * rinv * SCALE, 1024.0f);
    }
    GEO[tid] = make_float4(hx, hy, hz, u);
  }
  __syncthreads();
  float s1[4] = {0, 0, 0, 0};
  float v1[4][3] = {};
  float s2 = 0, v2x = 0, v2y = 0, v2z = 0, v3x = 0, v3y = 0, v3z = 0;
  const int jbase = part * 192;
  const int base = w * 48 + sq;
  // ---- pipeline prologue: load iter 0
  float4 g = GEO[base];
  int i0 = (int)g.w;
  float fr = g.w - (float)i0;
  const unsigned* row = T1 + i0 * ROWC;
  uint4 t1 = ((const uint4*)row)[idx];
  uint4 t3 = ((const uint4*)row)[16 + idx];
  unsigned u2 = row[128 + idx];
  unsigned u4 = row[144 + idx];
  unsigned u5 = row[160 + idx];
  uint2 esb = HSB[(jbase + base) * 16 + idx];
  uint2 evb = HVB[(jbase + base) * 16 + idx];
  for (int q = 0; q < 12; ++q) {
    // current stage registers
    float4 gc = g; float frc = fr;
    uint4 t1c = t1, t3c = t3;
    unsigned u2c = u2, u4c = u4, u5c = u5;
    uint2 esc = esb, evc = evb;
    // prefetch next stage
    if (q < 11) {
      int jl = base + (q + 1) * 4;
      g = GEO[jl];
      i0 = (int)g.w;
      fr = g.w - (float)i0;
      const unsigned* rn = T1 + i0 * ROWC;
      t1 = ((const uint4*)rn)[idx];
      t3 = ((const uint4*)rn)[16 + idx];
      u2 = rn[128 + idx];
      u4 = rn[144 + idx];
      u5 = rn[160 + idx];
      esb = HSB[(jbase + jl) * 16 + idx];
      evb = HVB[(jbase + jl) * 16 + idx];
    }
    // compute with current
    float esx = bl(esc.x), esy = bh(esc.x), esz = bl(esc.y), esw = bh(esc.y);
    float evx = bl(evc.x), evy = bh(evc.x), evz = bl(evc.y);
    s1[0] += esx * lp(t1c.x, frc); s1[1] += esy * lp(t1c.y, frc);
    s1[2] += esz * lp(t1c.z, frc); s1[3] += esw * lp(t1c.w, frc);
    float ax = esx * lp(t3c.x, frc), ay = esy * lp(t3c.y, frc);
    float az = esz * lp(t3c.z, frc), aw = esw * lp(t3c.w, frc);
    v1[0][0] += ax * gc.x; v1[0][1] += ax * gc.y; v1[0][2] += ax * gc.z;
    v1[1][0] += ay * gc.x; v1[1][1] += ay * gc.y; v1[1][2] += ay * gc.z;
    v1[2][0] += az * gc.x; v1[2][1] += az * gc.y; v1[2][2] += az * gc.z;
    v1[3][0] += aw * gc.x; v1[3][1] += aw * gc.y; v1[3][2] += aw * gc.z;
    float rr2 = lp(u2c, frc), rr4 = lp(u4c, frc), rr5 = lp(u5c, frc);
    float dt = evx * gc.x + evy * gc.y + evz * gc.z;
    s2 += dt * rr2;
    v2x += evx * rr4; v2y += evy * rr4; v2z += evz * rr4;
    v3x += (evy * gc.z - evz * gc.y) * rr5;
    v3y += (evz * gc.x - evx * gc.z) * rr5;
    v3z += (evx * gc.y - evy * gc.x) * rr5;
  }
  float vals[23] = {s1[0], s1[1], s1[2], s1[3],
                    v1[0][0], v1[0][1], v1[0][2], v1[1][0], v1[1][1], v1[1][2],
                    v1[2][0], v1[2][1], v1[2][2], v1[3][0], v1[3][1], v1[3][2],
                    s2, v2x, v2y, v2z, v3x, v3y, v3z};
#pragma unroll
  for (int k = 0; k < 23; ++k) {
    float v = vals[k];
    v += __shfl_xor(v, 16);
    v += __shfl_xor(v, 32);
    if (lane < 16) wb[w][lane][k] = v;
  }
  __syncthreads();
  for (int s = tid; s < 368; s += 256) {
    int l, sl;
    if (s < 64) { l = s >> 2; sl = s & 3; }
    else if (s < 80) { l = s - 64; sl = 16; }
    else if (s < 272) { int p = s - 80, f = p / 3, c = p - 3 * f; l = f >> 2; sl = 4 + 3 * (f & 3) + c; }
    else if (s < 320) { int p = s - 272, v = p / 3, c = p - 3 * v; l = v; sl = 17 + c; }
    else { int p = s - 320, v = p / 3, c = p - 3 * v; l = v; sl = 20 + c; }
    ws[WS_SLAB1 + (part * Nn + i) * 384 + s] =
        wb[0][l][sl] + wb[1][l][sl] + wb[2][l][sl] + wb[3][l][sl];
  }
}

// ------------------------------------------------------------- post t=1 -----
__global__ __launch_bounds__(256) void k_post1(const float* __restrict__ wmixs,
                                               const float* __restrict__ wmixv,
                                               const float* __restrict__ wgate,
                                               const float* __restrict__ wros,
                                               const float* __restrict__ wrov,
                                               float* __restrict__ ws,
                                               float* __restrict__ out) {
  const int i = blockIdx.x, tid = threadIdx.x;
  __shared__ float agg[368];
  __shared__ float ms[64], mvv[16][3], gate[16], hsn[64], hvns[16][4];
  const float inv = 1.0f / AVGF;
  const float* S = ws + WS_SLAB1 + i * 384;
  for (int s = tid; s < 368; s += 256)
    agg[s] = (S[s] + S[Nn * 384 + s] + S[2 * Nn * 384 + s] + S[3 * Nn * 384 + s]) * inv;
  __syncthreads();
  if (tid < 64) {
    const float* Wm = wmixs + 80 * 64;             // wmixs[1]
    float a = 0;
    for (int p = 0; p < 80; ++p) a = fmaf(agg[p], Wm[p * 64 + tid], a);
    ms[tid] = a;
  } else if (tid < 112) {
    int c = (tid - 64) >> 4, v = (tid - 64) & 15;
    const float* Wv = wmixv + 96 * 16;             // wmixv[1]
    float a = 0;
    for (int p = 0; p < 96; ++p) {
      int ai = (p < 64) ? (80 + p * 3 + c) : (p < 80 ? (272 + (p - 64) * 3 + c)
                                                     : (320 + (p - 80) * 3 + c));
      a = fmaf(agg[ai], Wv[p * 16 + v], a);
    }
    mvv[v][c] = a;
  }
  __syncthreads();
  if (tid < 64) {
    float m = ms[tid];
    hsn[tid] = m / (1.0f + expf(-m));
  } else if (tid < 80) {
    int v = tid - 64;
    const float* Wg = wgate + 64 * 16;             // wgate[1]
    float a = 0;
    for (int f = 0; f < 64; ++f) a = fmaf(ms[f], Wg[f * 16 + v], a);
    gate[v] = 1.0f / (1.0f + expf(-a));
  }
  __syncthreads();
  if (tid < 64) {
    int v = tid >> 2, c = tid & 3;
    hvns[v][c] = (c < 3) ? gate[v] * mvv[v][c] : 0.0f;
  }
  __syncthreads();
  if (tid < 32) {
    const float* Wr = wros + 64 * 32;              // wros[1]
    float a = ws[WS_OS + i * 32 + tid];
    for (int f = 0; f < 64; ++f) a = fmaf(hsn[f], Wr[f * 32 + tid], a);
    out[i * 32 + tid] = a;
  } else if (tid < 80) {
    int p = tid - 32, k = p / 3, c = p - 3 * k;
    const float* Wr = wrov + 16 * 16;              // wrov[1]
    float a = ws[WS_OV + i * 48 + p] + ws[WS_COM + c];
    for (int v = 0; v < 16; ++v) a = fmaf(hvns[v][c], Wr[v * 16 + k], a);
    out[Nn * 32 + i * 48 + p] = a;
  }
}

// ------------------------------------------------------------- launch -------
extern "C" void kernel_launch(void* const* d_in, const int* in_sizes, int n_in,
                              void* d_out, int out_size, void* d_ws, size_t ws_size,
                              hipStream_t stream) {
  const float* x     = (const float*)d_in[0];
  const float* embed = (const float*)d_in[1];
  const float* wns   = (const float*)d_in[2];
  const float* wnv   = (const float*)d_in[3];
  const float* w1    = (const float*)d_in[4];
  const float* b1    = (const float*)d_in[5];
  const float* w2    = (const float*)d_in[6];
  const float* wmixs = (const float*)d_in[7];
  const float* wmixv = (const float*)d_in[8];
  const float* wgate = (const float*)d_in[9];
  const float* wros  = (const float*)d_in[10];
  const float* wrov  = (const float*)d_in[11];
  float* ws = (float*)d_ws;
  float* out = (float*)d_out;

  hipLaunchKernelGGL(k_setup, dim3(259),    dim3(256), 0, stream, x, embed, wns, w1, b1, w2, ws);
  hipLaunchKernelGGL(k_edge0, dim3(Nn * 4), dim3(256), 0, stream, ws);
  hipLaunchKernelGGL(k_post0, dim3(Nn),     dim3(256), 0, stream,
                     wns, wnv, wmixs, wmixv, wgate, wros, wrov, ws);
  hipLaunchKernelGGL(k_edge1, dim3(Nn * 4), dim3(256), 0, stream, ws);
  hipLaunchKernelGGL(k_post1, dim3(Nn),     dim3(256), 0, stream,
                     wmixs, wmixv, wgate, wros, wrov, ws, out);
}